// Round 1
// baseline (2999.999 us; speedup 1.0000x reference)
//
#include <hip/hip_runtime.h>
#include <math.h>

#define N_NODES 10000
#define N_EDGES 100000
#define E_TOT   (N_EDGES + N_NODES)
#define PROJ    768
#define LN_EPS  1e-5f

__device__ __forceinline__ float elu_f(float x){ return x > 0.f ? x : expm1f(x); }

// ---------------- CSR build (by dst, with self loops appended) ----------------
__global__ void k_count(const int* __restrict__ ei, int* __restrict__ cnt){
  int e = blockIdx.x*blockDim.x + threadIdx.x;
  if (e >= E_TOT) return;
  int dst = (e < N_EDGES) ? ei[N_EDGES + e] : (e - N_EDGES);
  atomicAdd(&cnt[dst], 1);
}

__global__ void k_scan(const int* __restrict__ cnt, int* __restrict__ indptr){
  __shared__ int s[1024];
  __shared__ int s_running;
  int t = threadIdx.x;
  if (t == 0) s_running = 0;
  __syncthreads();
  for (int base = 0; base < N_NODES; base += 1024){
    int v = (base + t < N_NODES) ? cnt[base + t] : 0;
    s[t] = v; __syncthreads();
    for (int off = 1; off < 1024; off <<= 1){
      int add = (t >= off) ? s[t - off] : 0;
      __syncthreads();
      s[t] += add;
      __syncthreads();
    }
    int total = s[1023];
    int run = s_running;
    if (base + t < N_NODES) indptr[base + t] = run + s[t] - v;
    __syncthreads();
    if (t == 0) s_running = run + total;
    __syncthreads();
  }
  if (t == 0) indptr[N_NODES] = s_running;
}

__global__ void k_copy_int(const int* __restrict__ src, int* __restrict__ dst, int n){
  int i = blockIdx.x*blockDim.x + threadIdx.x;
  if (i < n) dst[i] = src[i];
}

__global__ void k_fill(const int* __restrict__ ei, int* __restrict__ pos, int* __restrict__ csr_src){
  int e = blockIdx.x*blockDim.x + threadIdx.x;
  if (e >= E_TOT) return;
  int s, d;
  if (e < N_EDGES){ s = ei[e]; d = ei[N_EDGES + e]; }
  else            { s = d = e - N_EDGES; }
  int p = atomicAdd(&pos[d], 1);
  csr_src[p] = s;
}

// ---------------- LayerNorm over 768, one block/row ----------------
__global__ void k_layernorm(const float* __restrict__ x, const float* __restrict__ w,
                            const float* __restrict__ b, float* __restrict__ y){
  int n = blockIdx.x;
  int t = threadIdx.x;
  const float* xr = x + (size_t)n*PROJ;
  float v0 = xr[t], v1 = xr[t+256], v2 = xr[t+512];
  float s  = v0+v1+v2;
  float s2 = v0*v0 + v1*v1 + v2*v2;
  #pragma unroll
  for (int off = 32; off; off >>= 1){ s += __shfl_down(s, off); s2 += __shfl_down(s2, off); }
  __shared__ float rs[4], rs2[4];
  __shared__ float s_mean, s_rstd;
  int wid = t >> 6, lane = t & 63;
  if (lane == 0){ rs[wid] = s; rs2[wid] = s2; }
  __syncthreads();
  if (t == 0){
    float S  = rs[0]+rs[1]+rs[2]+rs[3];
    float S2 = rs2[0]+rs2[1]+rs2[2]+rs2[3];
    float m  = S * (1.f/768.f);
    float var = S2 * (1.f/768.f) - m*m;
    s_mean = m; s_rstd = rsqrtf(var + LN_EPS);
  }
  __syncthreads();
  float m = s_mean, r = s_rstd;
  float* yr = y + (size_t)n*PROJ;
  yr[t]     = (v0-m)*r*w[t]     + b[t];
  yr[t+256] = (v1-m)*r*w[t+256] + b[t+256];
  yr[t+512] = (v2-m)*r*w[t+512] + b[t+512];
}

// ---------------- fp32 GEMM:  C[m,n] = sum_k A[m,k] * W[n,k]  (A row-major, W row-major [N,K])
// EPI: 0 = none; 1 = elu(v + bias[n]); 2 = elu(v + bias[n] + res[m,n])
template<int EPI>
__global__ void k_gemm_nt(const float* __restrict__ A, int lda,
                          const float* __restrict__ W,
                          float* __restrict__ C, int ldc,
                          int M, int N, int K,
                          const float* __restrict__ bias,
                          const float* __restrict__ res, int ldres){
  __shared__ float As[16][72];
  __shared__ float Bs[16][72];
  const int bm = blockIdx.y*64, bn = blockIdx.x*64;
  const int tid = threadIdx.x;
  const int tx = tid & 15, ty = tid >> 4;
  const int lrow = tid >> 2;        // 0..63
  const int lkq  = (tid & 3) * 4;   // 0,4,8,12
  float acc[4][4] = {};
  for (int k0 = 0; k0 < K; k0 += 16){
    float4 av = make_float4(0,0,0,0), bv = make_float4(0,0,0,0);
    int am = bm + lrow;
    if (am < M) av = *(const float4*)(A + (size_t)am*lda + k0 + lkq);
    int wn = bn + lrow;
    if (wn < N) bv = *(const float4*)(W + (size_t)wn*K + k0 + lkq);
    __syncthreads();
    As[lkq+0][lrow]=av.x; As[lkq+1][lrow]=av.y; As[lkq+2][lrow]=av.z; As[lkq+3][lrow]=av.w;
    Bs[lkq+0][lrow]=bv.x; Bs[lkq+1][lrow]=bv.y; Bs[lkq+2][lrow]=bv.z; Bs[lkq+3][lrow]=bv.w;
    __syncthreads();
    #pragma unroll
    for (int k = 0; k < 16; k++){
      float a[4], bb[4];
      #pragma unroll
      for (int i = 0; i < 4; i++) a[i]  = As[k][ty*4+i];
      #pragma unroll
      for (int j = 0; j < 4; j++) bb[j] = Bs[k][tx*4+j];
      #pragma unroll
      for (int i = 0; i < 4; i++)
        #pragma unroll
        for (int j = 0; j < 4; j++)
          acc[i][j] = fmaf(a[i], bb[j], acc[i][j]);
    }
  }
  #pragma unroll
  for (int i = 0; i < 4; i++){
    int m = bm + ty*4 + i;
    if (m >= M) continue;
    #pragma unroll
    for (int j = 0; j < 4; j++){
      int nn = bn + tx*4 + j;
      if (nn >= N) continue;
      float v = acc[i][j];
      if (EPI == 1) v = elu_f(v + bias[nn]);
      else if (EPI == 2) v = elu_f(v + bias[nn] + res[(size_t)m*ldres + nn]);
      C[(size_t)m*ldc + nn] = v;
    }
  }
}

// ---------------- attention coefficients: als/ald[n,h] = sum_c h[n,h,c]*a[h,c]
template<int H, int C>
__global__ void k_attn_coef(const float* __restrict__ hlin,
                            const float* __restrict__ a_src,
                            const float* __restrict__ a_dst,
                            float* __restrict__ als, float* __restrict__ ald){
  int n = blockIdx.x;
  int wid = threadIdx.x >> 6, lane = threadIdx.x & 63;
  const float* hr = hlin + (size_t)n*H*C + wid*C;
  float ss = 0.f, sd = 0.f;
  for (int c = lane; c < C; c += 64){
    float hv = hr[c];
    ss += hv * a_src[wid*C + c];
    sd += hv * a_dst[wid*C + c];
  }
  #pragma unroll
  for (int off = 32; off; off >>= 1){ ss += __shfl_down(ss, off); sd += __shfl_down(sd, off); }
  if (lane == 0){ als[n*H + wid] = ss; ald[n*H + wid] = sd; }
}

// ---------------- per-dst-node softmax + aggregate, one block/node ----------------
template<int H, int C, bool CONCAT, bool DO_ELU>
__global__ void k_attn_agg(const float* __restrict__ hlin,
                           const float* __restrict__ als, const float* __restrict__ ald,
                           const int* __restrict__ indptr, const int* __restrict__ csr_src,
                           const float* __restrict__ bias,
                           float* __restrict__ out, int ldo, int col0){
  constexpr int TOT = H*C;
  constexpr int PER = (TOT + 255) / 256;
  int n = blockIdx.x;
  int tid = threadIdx.x;
  int beg = indptr[n], end = indptr[n+1], deg = end - beg;

  __shared__ float s_m[H], s_deninv[H], s_ald[H];
  __shared__ float s_alpha[64][H];
  __shared__ int   s_src[64];

  if (tid < H) s_ald[tid] = ald[n*H + tid];
  __syncthreads();
  if (tid < H){
    float m = -INFINITY;
    for (int e = beg; e < end; e++){
      int s = csr_src[e];
      float v = als[s*H + tid] + s_ald[tid];
      v = v > 0.f ? v : 0.2f*v;
      m = fmaxf(m, v);
    }
    float den = 0.f;
    for (int e = beg; e < end; e++){
      int s = csr_src[e];
      float v = als[s*H + tid] + s_ald[tid];
      v = v > 0.f ? v : 0.2f*v;
      den += expf(v - m);
    }
    s_m[tid] = m;
    s_deninv[tid] = 1.f / (den + 1e-16f);
  }
  __syncthreads();

  int hof[PER];
  #pragma unroll
  for (int p = 0; p < PER; p++) hof[p] = (tid + p*256) / C;

  float acc[PER];
  #pragma unroll
  for (int p = 0; p < PER; p++) acc[p] = 0.f;

  for (int base = 0; base < deg; base += 64){
    int chunk = min(64, deg - base);
    __syncthreads();
    if (tid < chunk) s_src[tid] = csr_src[beg + base + tid];
    __syncthreads();
    for (int idx = tid; idx < chunk*H; idx += 256){
      int e = idx / H, h = idx - e*H;
      float v = als[s_src[e]*H + h] + s_ald[h];
      v = v > 0.f ? v : 0.2f*v;
      s_alpha[e][h] = expf(v - s_m[h]) * s_deninv[h];
    }
    __syncthreads();
    for (int e = 0; e < chunk; e++){
      const float* hr = hlin + (size_t)s_src[e]*TOT;
      #pragma unroll
      for (int p = 0; p < PER; p++){
        int idx = tid + p*256;
        if (TOT % 256 == 0 || idx < TOT)
          acc[p] += hr[idx] * s_alpha[e][hof[p]];
      }
    }
  }

  if (CONCAT){
    #pragma unroll
    for (int p = 0; p < PER; p++){
      int idx = tid + p*256;
      if (TOT % 256 == 0 || idx < TOT){
        float v = acc[p] + bias[idx];
        if (DO_ELU) v = elu_f(v);
        out[(size_t)n*ldo + col0 + idx] = v;
      }
    }
  } else {
    // mean over heads; requires 256 % C == 0 (C=128)
    float sum = 0.f;
    #pragma unroll
    for (int p = 0; p < PER; p++) sum += acc[p];
    __shared__ float s_red[2][128];
    s_red[tid >> 7][tid & 127] = sum;
    __syncthreads();
    if (tid < 128){
      float v = (s_red[0][tid] + s_red[1][tid]) * (1.f/(float)H) + bias[tid];
      out[(size_t)n*ldo + tid] = v;
    }
  }
}

// ---------------- launch ----------------
extern "C" void kernel_launch(void* const* d_in, const int* in_sizes, int n_in,
                              void* d_out, int out_size, void* d_ws, size_t ws_size,
                              hipStream_t stream){
  const float* x      = (const float*)d_in[0];
  const int*   ei     = (const int*)  d_in[1];
  const float* proj_W = (const float*)d_in[2];
  const float* proj_b = (const float*)d_in[3];
  const float* norm_w = (const float*)d_in[4];
  const float* norm_b = (const float*)d_in[5];
  const float* g1_W   = (const float*)d_in[6];
  const float* g1_as  = (const float*)d_in[7];
  const float* g1_ad  = (const float*)d_in[8];
  const float* g1_b   = (const float*)d_in[9];
  const float* g2_W   = (const float*)d_in[10];
  const float* g2_as  = (const float*)d_in[11];
  const float* g2_ad  = (const float*)d_in[12];
  const float* g2_b   = (const float*)d_in[13];
  const float* uni_W  = (const float*)d_in[14];
  const float* uni_b  = (const float*)d_in[15];
  const float* fnorm_w= (const float*)d_in[16];
  const float* fnorm_b= (const float*)d_in[17];
  const float* fg_W   = (const float*)d_in[18];
  const float* fg_as  = (const float*)d_in[19];
  const float* fg_ad  = (const float*)d_in[20];
  const float* fg_b   = (const float*)d_in[21];
  float* out = (float*)d_out;

  float* w = (float*)d_ws;
  float* bufA = w; w += 7680000;   // h
  float* bufB = w; w += 7680000;   // hn / h_next (swapped)
  float* bufC = w; w += 7680000;   // lin1 out [10000,768]
  float* bufD = w; w += 1920000;   // lin2 out [10000,192]
  float* bufE = w; w += 10240000;  // cat [10000,960] / final lin [10000,1024]
  float* als  = w; w += 80000;
  float* ald  = w; w += 80000;
  int* iw = (int*)w;
  int* cnt     = iw; iw += 10016;
  int* indptr  = iw; iw += 10016;
  int* pos     = iw; iw += 10016;
  int* csr_src = iw; iw += 110016;

  hipMemsetAsync(cnt, 0, N_NODES*sizeof(int), stream);
  k_count<<<(E_TOT+255)/256, 256, 0, stream>>>(ei, cnt);
  k_scan<<<1, 1024, 0, stream>>>(cnt, indptr);
  k_copy_int<<<(N_NODES+255)/256, 256, 0, stream>>>(indptr, pos, N_NODES);
  k_fill<<<(E_TOT+255)/256, 256, 0, stream>>>(ei, pos, csr_src);

  dim3 blk(256);
  // h = elu(x @ proj_W.T + proj_b)
  k_gemm_nt<1><<<dim3(768/64, (N_NODES+63)/64), blk, 0, stream>>>(
      x, 384, proj_W, bufA, 768, N_NODES, 768, 384, proj_b, nullptr, 0);

  float* cur = bufA;
  float* oth = bufB;
  for (int i = 0; i < 4; i++){
    k_layernorm<<<N_NODES, 256, 0, stream>>>(cur, norm_w + i*768, norm_b + i*768, oth);
    k_gemm_nt<0><<<dim3(12, 157), blk, 0, stream>>>(oth, 768, g1_W + (size_t)i*768*768, bufC, 768, N_NODES, 768, 768, nullptr, nullptr, 0);
    k_gemm_nt<0><<<dim3(3, 157),  blk, 0, stream>>>(oth, 768, g2_W + (size_t)i*192*768, bufD, 192, N_NODES, 192, 768, nullptr, nullptr, 0);
    k_attn_coef<4,192><<<N_NODES, 256, 0, stream>>>(bufC, g1_as + i*768, g1_ad + i*768, als, ald);
    k_attn_agg<4,192,true,true><<<N_NODES, 256, 0, stream>>>(bufC, als, ald, indptr, csr_src, g1_b + i*768, bufE, 960, 0);
    k_attn_coef<2,96><<<N_NODES, 128, 0, stream>>>(bufD, g2_as + i*192, g2_ad + i*192, als, ald);
    k_attn_agg<2,96,true,true><<<N_NODES, 256, 0, stream>>>(bufD, als, ald, indptr, csr_src, g2_b + i*192, bufE, 960, 768);
    // h = elu(res + cat @ uni_W.T + uni_b)
    k_gemm_nt<2><<<dim3(12, 157), blk, 0, stream>>>(bufE, 960, uni_W + (size_t)i*768*960, oth, 768, N_NODES, 768, 960, uni_b + i*768, cur, 768);
    float* t = cur; cur = oth; oth = t;
  }
  k_layernorm<<<N_NODES, 256, 0, stream>>>(cur, fnorm_w, fnorm_b, oth);
  k_gemm_nt<0><<<dim3(16, 157), blk, 0, stream>>>(oth, 768, fg_W, bufE, 1024, N_NODES, 1024, 768, nullptr, nullptr, 0);
  k_attn_coef<8,128><<<N_NODES, 512, 0, stream>>>(bufE, fg_as, fg_ad, als, ald);
  k_attn_agg<8,128,false,false><<<N_NODES, 256, 0, stream>>>(bufE, als, ald, indptr, csr_src, fg_b, out, 128, 0);
}

// Round 2
// 1197.354 us; speedup vs baseline: 2.5055x; 2.5055x over previous
//
#include <hip/hip_runtime.h>
#include <math.h>

#define N_NODES 10000
#define N_EDGES 100000
#define E_TOT   (N_EDGES + N_NODES)
#define PROJ    768
#define LN_EPS  1e-5f

typedef __attribute__((ext_vector_type(8))) short bf16x8;
typedef __attribute__((ext_vector_type(4))) float f32x4;

__device__ __forceinline__ float elu_f(float x){ return x > 0.f ? x : expm1f(x); }
__device__ __forceinline__ float bf2f(unsigned short u){ return __uint_as_float(((unsigned int)u) << 16); }
__device__ __forceinline__ unsigned short f2bf(float f){
  unsigned int u = __float_as_uint(f);
  return (unsigned short)((u + 0x7FFFu + ((u >> 16) & 1u)) >> 16);
}

#define GLOAD16(gp, lp) __builtin_amdgcn_global_load_lds((const __attribute__((address_space(1))) void*)(gp), (__attribute__((address_space(3))) void*)(lp), 16, 0, 0)

// ---------------- CSR build (by dst, self loops appended) ----------------
__global__ void k_count(const int* __restrict__ ei, int* __restrict__ cnt){
  int e = blockIdx.x*blockDim.x + threadIdx.x;
  if (e >= E_TOT) return;
  int dst = (e < N_EDGES) ? ei[N_EDGES + e] : (e - N_EDGES);
  atomicAdd(&cnt[dst], 1);
}

__global__ void k_scan(const int* __restrict__ cnt, int* __restrict__ indptr){
  __shared__ int s[1024];
  __shared__ int s_running;
  int t = threadIdx.x;
  if (t == 0) s_running = 0;
  __syncthreads();
  for (int base = 0; base < N_NODES; base += 1024){
    int v = (base + t < N_NODES) ? cnt[base + t] : 0;
    s[t] = v; __syncthreads();
    for (int off = 1; off < 1024; off <<= 1){
      int add = (t >= off) ? s[t - off] : 0;
      __syncthreads();
      s[t] += add;
      __syncthreads();
    }
    int total = s[1023];
    int run = s_running;
    if (base + t < N_NODES) indptr[base + t] = run + s[t] - v;
    __syncthreads();
    if (t == 0) s_running = run + total;
    __syncthreads();
  }
  if (t == 0) indptr[N_NODES] = s_running;
}

__global__ void k_copy_int(const int* __restrict__ src, int* __restrict__ dst, int n){
  int i = blockIdx.x*blockDim.x + threadIdx.x;
  if (i < n) dst[i] = src[i];
}

__global__ void k_fill(const int* __restrict__ ei, int* __restrict__ pos, int* __restrict__ csr_src){
  int e = blockIdx.x*blockDim.x + threadIdx.x;
  if (e >= E_TOT) return;
  int s, d;
  if (e < N_EDGES){ s = ei[e]; d = ei[N_EDGES + e]; }
  else            { s = d = e - N_EDGES; }
  int p = atomicAdd(&pos[d], 1);
  csr_src[p] = s;
}

__global__ void k_f2bf_arr(const float* __restrict__ in, unsigned short* __restrict__ out, int n){
  int i = blockIdx.x*blockDim.x + threadIdx.x;
  if (i < n) out[i] = f2bf(in[i]);
}

// ---------------- LayerNorm over 768 -> bf16 output ----------------
__global__ void k_layernorm_bf(const float* __restrict__ x, const float* __restrict__ w,
                               const float* __restrict__ b, unsigned short* __restrict__ y){
  int n = blockIdx.x;
  int t = threadIdx.x;
  const float* xr = x + (size_t)n*PROJ;
  float v0 = xr[t], v1 = xr[t+256], v2 = xr[t+512];
  float s  = v0+v1+v2;
  float s2 = v0*v0 + v1*v1 + v2*v2;
  #pragma unroll
  for (int off = 32; off; off >>= 1){ s += __shfl_down(s, off); s2 += __shfl_down(s2, off); }
  __shared__ float rs[4], rs2[4];
  __shared__ float s_mean, s_rstd;
  int wid = t >> 6, lane = t & 63;
  if (lane == 0){ rs[wid] = s; rs2[wid] = s2; }
  __syncthreads();
  if (t == 0){
    float S  = rs[0]+rs[1]+rs[2]+rs[3];
    float S2 = rs2[0]+rs2[1]+rs2[2]+rs2[3];
    float m  = S * (1.f/768.f);
    float var = S2 * (1.f/768.f) - m*m;
    s_mean = m; s_rstd = rsqrtf(var + LN_EPS);
  }
  __syncthreads();
  float m = s_mean, r = s_rstd;
  unsigned short* yr = y + (size_t)n*PROJ;
  yr[t]     = f2bf((v0-m)*r*w[t]     + b[t]);
  yr[t+256] = f2bf((v1-m)*r*w[t+256] + b[t+256]);
  yr[t+512] = f2bf((v2-m)*r*w[t+512] + b[t+512]);
}

// ---------------- bf16 MFMA GEMM:  C[m,n] = sum_k A[m,k]*W[n,k]
// EPI 0: bf16 out, no epilogue; EPI 1: f32 out elu(v+bias); EPI 2: f32 out elu(v+bias+res)
template<int EPI>
__global__ __launch_bounds__(256)
void k_gemm_mfma(const unsigned short* __restrict__ A, int lda,
                 const unsigned short* __restrict__ W,
                 void* __restrict__ Cv, int ldc,
                 int M, int N, int K,
                 const float* __restrict__ bias,
                 const float* __restrict__ res, int ldres){
  __shared__ unsigned short As[128*32];
  __shared__ unsigned short Bs[128*32];
  const int bm = blockIdx.y*128, bn = blockIdx.x*128;
  const int tid = threadIdx.x;
  const int lane = tid & 63, wid = tid >> 6;
  const int wm = wid >> 1, wn = wid & 1;

  const int rowA0 = tid >> 2;       // 0..63; inst1 adds 64
  const int c8 = (tid & 3) << 3;    // 0,8,16,24

  f32x4 acc[4][4];
  #pragma unroll
  for (int i=0;i<4;i++)
    #pragma unroll
    for (int j=0;j<4;j++) acc[i][j] = (f32x4){0.f,0.f,0.f,0.f};

  const size_t amr0 = (size_t)min(bm + rowA0,      M-1) * lda;
  const size_t amr1 = (size_t)min(bm + rowA0 + 64, M-1) * lda;
  const size_t wnr0 = (size_t)min(bn + rowA0,      N-1) * K;
  const size_t wnr1 = (size_t)min(bn + rowA0 + 64, N-1) * K;

  unsigned short* ldsA0 = &As[(wid*64)*8];
  unsigned short* ldsA1 = &As[(256 + wid*64)*8];
  unsigned short* ldsB0 = &Bs[(wid*64)*8];
  unsigned short* ldsB1 = &Bs[(256 + wid*64)*8];

  for (int k0 = 0; k0 < K; k0 += 32){
    __syncthreads();
    GLOAD16(A + amr0 + k0 + c8, ldsA0);
    GLOAD16(A + amr1 + k0 + c8, ldsA1);
    GLOAD16(W + wnr0 + k0 + c8, ldsB0);
    GLOAD16(W + wnr1 + k0 + c8, ldsB1);
    __syncthreads();

    bf16x8 af[4], bfr[4];
    const int kb8 = (lane >> 4) * 8;
    #pragma unroll
    for (int mi=0; mi<4; mi++){
      int r = wm*64 + mi*16 + (lane & 15);
      af[mi] = *(const bf16x8*)&As[r*32 + kb8];
    }
    #pragma unroll
    for (int ni=0; ni<4; ni++){
      int r = wn*64 + ni*16 + (lane & 15);
      bfr[ni] = *(const bf16x8*)&Bs[r*32 + kb8];
    }
    #pragma unroll
    for (int mi=0; mi<4; mi++)
      #pragma unroll
      for (int ni=0; ni<4; ni++)
        acc[mi][ni] = __builtin_amdgcn_mfma_f32_16x16x32_bf16(af[mi], bfr[ni], acc[mi][ni], 0,0,0);
  }

  const int mrow0 = bm + wm*64 + ((lane>>4)<<2);
  const int ncol0 = bn + wn*64 + (lane & 15);
  #pragma unroll
  for (int mi=0; mi<4; mi++){
    #pragma unroll
    for (int r=0; r<4; r++){
      int m = mrow0 + mi*16 + r;
      if (m >= M) continue;
      #pragma unroll
      for (int ni=0; ni<4; ni++){
        int n = ncol0 + ni*16;
        if (n >= N) continue;
        float v = acc[mi][ni][r];
        if (EPI == 0){
          ((unsigned short*)Cv)[(size_t)m*ldc + n] = f2bf(v);
        } else if (EPI == 1){
          ((float*)Cv)[(size_t)m*ldc + n] = elu_f(v + bias[n]);
        } else {
          ((float*)Cv)[(size_t)m*ldc + n] = elu_f(v + bias[n] + res[(size_t)m*ldres + n]);
        }
      }
    }
  }
}

// ---------------- attention coefficients (bf16 hlin) ----------------
template<int H, int C>
__global__ void k_attn_coef(const unsigned short* __restrict__ hlin,
                            const float* __restrict__ a_src,
                            const float* __restrict__ a_dst,
                            float* __restrict__ als, float* __restrict__ ald){
  int n = blockIdx.x;
  int wid = threadIdx.x >> 6, lane = threadIdx.x & 63;
  const unsigned short* hr = hlin + (size_t)n*H*C + wid*C;
  float ss = 0.f, sd = 0.f;
  for (int c = lane; c < C; c += 64){
    float hv = bf2f(hr[c]);
    ss += hv * a_src[wid*C + c];
    sd += hv * a_dst[wid*C + c];
  }
  #pragma unroll
  for (int off = 32; off; off >>= 1){ ss += __shfl_down(ss, off); sd += __shfl_down(sd, off); }
  if (lane == 0){ als[n*H + wid] = ss; ald[n*H + wid] = sd; }
}

// ---------------- per-dst-node softmax + aggregate ----------------
template<int H, int C, bool CONCAT, bool DO_ELU>
__global__ void k_attn_agg(const unsigned short* __restrict__ hlin,
                           const float* __restrict__ als, const float* __restrict__ ald,
                           const int* __restrict__ indptr, const int* __restrict__ csr_src,
                           const float* __restrict__ bias,
                           void* __restrict__ outv, int ldo, int col0){
  constexpr int TOT = H*C;
  constexpr int PER = (TOT + 255) / 256;
  int n = blockIdx.x;
  int tid = threadIdx.x;
  int beg = indptr[n], end = indptr[n+1], deg = end - beg;

  __shared__ float s_m[H], s_deninv[H], s_ald[H];
  __shared__ float s_alpha[64][H];
  __shared__ int   s_src[64];

  if (tid < H) s_ald[tid] = ald[n*H + tid];
  __syncthreads();
  if (tid < H){
    float m = -INFINITY;
    for (int e = beg; e < end; e++){
      int s = csr_src[e];
      float v = als[s*H + tid] + s_ald[tid];
      v = v > 0.f ? v : 0.2f*v;
      m = fmaxf(m, v);
    }
    float den = 0.f;
    for (int e = beg; e < end; e++){
      int s = csr_src[e];
      float v = als[s*H + tid] + s_ald[tid];
      v = v > 0.f ? v : 0.2f*v;
      den += expf(v - m);
    }
    s_m[tid] = m;
    s_deninv[tid] = 1.f / (den + 1e-16f);
  }
  __syncthreads();

  int hof[PER];
  #pragma unroll
  for (int p = 0; p < PER; p++) hof[p] = (tid + p*256) / C;

  float acc[PER];
  #pragma unroll
  for (int p = 0; p < PER; p++) acc[p] = 0.f;

  for (int base = 0; base < deg; base += 64){
    int chunk = min(64, deg - base);
    __syncthreads();
    if (tid < chunk) s_src[tid] = csr_src[beg + base + tid];
    __syncthreads();
    for (int idx = tid; idx < chunk*H; idx += 256){
      int e = idx / H, h = idx - e*H;
      float v = als[s_src[e]*H + h] + s_ald[h];
      v = v > 0.f ? v : 0.2f*v;
      s_alpha[e][h] = expf(v - s_m[h]) * s_deninv[h];
    }
    __syncthreads();
    for (int e = 0; e < chunk; e++){
      const unsigned short* hr = hlin + (size_t)s_src[e]*TOT;
      #pragma unroll
      for (int p = 0; p < PER; p++){
        int idx = tid + p*256;
        if (TOT % 256 == 0 || idx < TOT)
          acc[p] += bf2f(hr[idx]) * s_alpha[e][hof[p]];
      }
    }
  }

  if (CONCAT){
    unsigned short* out = (unsigned short*)outv;
    #pragma unroll
    for (int p = 0; p < PER; p++){
      int idx = tid + p*256;
      if (TOT % 256 == 0 || idx < TOT){
        float v = acc[p] + bias[idx];
        if (DO_ELU) v = elu_f(v);
        out[(size_t)n*ldo + col0 + idx] = f2bf(v);
      }
    }
  } else {
    float* out = (float*)outv;
    float sum = 0.f;
    #pragma unroll
    for (int p = 0; p < PER; p++) sum += acc[p];
    __shared__ float s_red[2][128];
    s_red[tid >> 7][tid & 127] = sum;
    __syncthreads();
    if (tid < 128){
      float v = (s_red[0][tid] + s_red[1][tid]) * (1.f/(float)H) + bias[tid];
      out[(size_t)n*ldo + tid] = v;
    }
  }
}

// ---------------- launch ----------------
extern "C" void kernel_launch(void* const* d_in, const int* in_sizes, int n_in,
                              void* d_out, int out_size, void* d_ws, size_t ws_size,
                              hipStream_t stream){
  const float* x      = (const float*)d_in[0];
  const int*   ei     = (const int*)  d_in[1];
  const float* proj_W = (const float*)d_in[2];
  const float* proj_b = (const float*)d_in[3];
  const float* norm_w = (const float*)d_in[4];
  const float* norm_b = (const float*)d_in[5];
  const float* g1_W   = (const float*)d_in[6];
  const float* g1_as  = (const float*)d_in[7];
  const float* g1_ad  = (const float*)d_in[8];
  const float* g1_b   = (const float*)d_in[9];
  const float* g2_W   = (const float*)d_in[10];
  const float* g2_as  = (const float*)d_in[11];
  const float* g2_ad  = (const float*)d_in[12];
  const float* g2_b   = (const float*)d_in[13];
  const float* uni_W  = (const float*)d_in[14];
  const float* uni_b  = (const float*)d_in[15];
  const float* fnorm_w= (const float*)d_in[16];
  const float* fnorm_b= (const float*)d_in[17];
  const float* fg_W   = (const float*)d_in[18];
  const float* fg_as  = (const float*)d_in[19];
  const float* fg_ad  = (const float*)d_in[20];
  const float* fg_b   = (const float*)d_in[21];

  float* w = (float*)d_ws;
  float* h    = w; w += 7680000;                          // fp32 h
  float* h2   = w; w += 7680000;                          // fp32 ping-pong
  unsigned short* lin1 = (unsigned short*)w; w += 5120000; // bf16 [10000,1024] (also 768-wide)
  unsigned short* lin2 = (unsigned short*)w; w += 960000;  // bf16 [10000,192]
  unsigned short* hnb  = (unsigned short*)w; w += 3840000; // bf16 [10000,768]; hosts x_bf16 first
  unsigned short* catb = (unsigned short*)w; w += 4800000; // bf16 [10000,960]
  unsigned short* wb   = (unsigned short*)w; w += 3489792; // bf16 weights
  float* als  = w; w += 80000;
  float* ald  = w; w += 80000;
  int* iw = (int*)w;
  int* cnt     = iw; iw += 10016;
  int* indptr  = iw; iw += 10016;
  int* pos     = iw; iw += 10016;
  int* csr_src = iw; iw += 110016;

  unsigned short* wb_proj = wb;
  unsigned short* wb_g1   = wb_proj + 294912;
  unsigned short* wb_g2   = wb_g1 + 2359296;
  unsigned short* wb_uni  = wb_g2 + 589824;
  unsigned short* wb_fg   = wb_uni + 2949120;

  // CSR
  hipMemsetAsync(cnt, 0, N_NODES*sizeof(int), stream);
  k_count<<<(E_TOT+255)/256, 256, 0, stream>>>(ei, cnt);
  k_scan<<<1, 1024, 0, stream>>>(cnt, indptr);
  k_copy_int<<<(N_NODES+255)/256, 256, 0, stream>>>(indptr, pos, N_NODES);
  k_fill<<<(E_TOT+255)/256, 256, 0, stream>>>(ei, pos, csr_src);

  // fp32 -> bf16 converts
  k_f2bf_arr<<<(3840000+255)/256, 256, 0, stream>>>(x, hnb, 3840000);
  k_f2bf_arr<<<(294912+255)/256,  256, 0, stream>>>(proj_W, wb_proj, 294912);
  k_f2bf_arr<<<(2359296+255)/256, 256, 0, stream>>>(g1_W, wb_g1, 2359296);
  k_f2bf_arr<<<(589824+255)/256,  256, 0, stream>>>(g2_W, wb_g2, 589824);
  k_f2bf_arr<<<(2949120+255)/256, 256, 0, stream>>>(uni_W, wb_uni, 2949120);
  k_f2bf_arr<<<(786432+255)/256,  256, 0, stream>>>(fg_W, wb_fg, 786432);

  dim3 blk(256);
  const int GY = (N_NODES + 127) / 128;  // 79

  // h = elu(x @ proj_W.T + proj_b)
  k_gemm_mfma<1><<<dim3(6, GY), blk, 0, stream>>>(hnb, 384, wb_proj, h, 768, N_NODES, 768, 384, proj_b, nullptr, 0);

  float* cur = h;
  float* oth = h2;
  for (int i = 0; i < 4; i++){
    k_layernorm_bf<<<N_NODES, 256, 0, stream>>>(cur, norm_w + i*768, norm_b + i*768, hnb);
    k_gemm_mfma<0><<<dim3(6, GY), blk, 0, stream>>>(hnb, 768, wb_g1 + (size_t)i*589824, lin1, 768, N_NODES, 768, 768, nullptr, nullptr, 0);
    k_gemm_mfma<0><<<dim3(2, GY), blk, 0, stream>>>(hnb, 768, wb_g2 + (size_t)i*147456, lin2, 192, N_NODES, 192, 768, nullptr, nullptr, 0);
    k_attn_coef<4,192><<<N_NODES, 256, 0, stream>>>(lin1, g1_as + i*768, g1_ad + i*768, als, ald);
    k_attn_agg<4,192,true,true><<<N_NODES, 256, 0, stream>>>(lin1, als, ald, indptr, csr_src, g1_b + i*768, catb, 960, 0);
    k_attn_coef<2,96><<<N_NODES, 128, 0, stream>>>(lin2, g2_as + i*192, g2_ad + i*192, als, ald);
    k_attn_agg<2,96,true,true><<<N_NODES, 256, 0, stream>>>(lin2, als, ald, indptr, csr_src, g2_b + i*192, catb, 960, 768);
    // h = elu(res + cat @ uni_W.T + uni_b)
    k_gemm_mfma<2><<<dim3(6, GY), blk, 0, stream>>>(catb, 960, wb_uni + (size_t)i*737280, oth, 768, N_NODES, 768, 960, uni_b + i*768, cur, 768);
    float* t = cur; cur = oth; oth = t;
  }

  k_layernorm_bf<<<N_NODES, 256, 0, stream>>>(cur, fnorm_w, fnorm_b, hnb);
  k_gemm_mfma<0><<<dim3(8, GY), blk, 0, stream>>>(hnb, 768, wb_fg, lin1, 1024, N_NODES, 1024, 768, nullptr, nullptr, 0);
  k_attn_coef<8,128><<<N_NODES, 512, 0, stream>>>(lin1, fg_as, fg_ad, als, ald);
  k_attn_agg<8,128,false,false><<<N_NODES, 256, 0, stream>>>(lin1, als, ald, indptr, csr_src, fg_b, d_out, 128, 0);
}

// Round 3
// 977.250 us; speedup vs baseline: 3.0698x; 1.2252x over previous
//
#include <hip/hip_runtime.h>
#include <math.h>

#define N_NODES 10000
#define N_EDGES 100000
#define E_TOT   (N_EDGES + N_NODES)
#define PROJ    768
#define LN_EPS  1e-5f

typedef __attribute__((ext_vector_type(8))) short bf16x8;
typedef __attribute__((ext_vector_type(4))) short bf16x4;
typedef __attribute__((ext_vector_type(4))) float f32x4;

__device__ __forceinline__ float elu_f(float x){ return x > 0.f ? x : expm1f(x); }
__device__ __forceinline__ float bf2f(unsigned short u){ return __uint_as_float(((unsigned int)u) << 16); }
__device__ __forceinline__ unsigned short f2bf(float f){
  unsigned int u = __float_as_uint(f);
  return (unsigned short)((u + 0x7FFFu + ((u >> 16) & 1u)) >> 16);
}

#define GLOAD16(gp, lp) __builtin_amdgcn_global_load_lds((const __attribute__((address_space(1))) void*)(gp), (__attribute__((address_space(3))) void*)(lp), 16, 0, 0)

// ---------------- CSR build (by dst, self loops appended) ----------------
__global__ void k_count(const int* __restrict__ ei, int* __restrict__ cnt){
  int e = blockIdx.x*blockDim.x + threadIdx.x;
  if (e >= E_TOT) return;
  int dst = (e < N_EDGES) ? ei[N_EDGES + e] : (e - N_EDGES);
  atomicAdd(&cnt[dst], 1);
}

__global__ void k_scan(const int* __restrict__ cnt, int* __restrict__ indptr){
  __shared__ int s[1024];
  __shared__ int s_running;
  int t = threadIdx.x;
  if (t == 0) s_running = 0;
  __syncthreads();
  for (int base = 0; base < N_NODES; base += 1024){
    int v = (base + t < N_NODES) ? cnt[base + t] : 0;
    s[t] = v; __syncthreads();
    for (int off = 1; off < 1024; off <<= 1){
      int add = (t >= off) ? s[t - off] : 0;
      __syncthreads();
      s[t] += add;
      __syncthreads();
    }
    int total = s[1023];
    int run = s_running;
    if (base + t < N_NODES) indptr[base + t] = run + s[t] - v;
    __syncthreads();
    if (t == 0) s_running = run + total;
    __syncthreads();
  }
  if (t == 0) indptr[N_NODES] = s_running;
}

__global__ void k_copy_int(const int* __restrict__ src, int* __restrict__ dst, int n){
  int i = blockIdx.x*blockDim.x + threadIdx.x;
  if (i < n) dst[i] = src[i];
}

__global__ void k_fill(const int* __restrict__ ei, int* __restrict__ pos, int* __restrict__ csr_src){
  int e = blockIdx.x*blockDim.x + threadIdx.x;
  if (e >= E_TOT) return;
  int s, d;
  if (e < N_EDGES){ s = ei[e]; d = ei[N_EDGES + e]; }
  else            { s = d = e - N_EDGES; }
  int p = atomicAdd(&pos[d], 1);
  csr_src[p] = s;
}

__global__ void k_f2bf_arr4(const float4* __restrict__ in, ushort4* __restrict__ out, int n4){
  int i = blockIdx.x*blockDim.x + threadIdx.x;
  if (i < n4){
    float4 v = in[i];
    ushort4 o;
    o.x = f2bf(v.x); o.y = f2bf(v.y); o.z = f2bf(v.z); o.w = f2bf(v.w);
    out[i] = o;
  }
}

// ---------------- LayerNorm over 768 -> bf16 output ----------------
__global__ void k_layernorm_bf(const float* __restrict__ x, const float* __restrict__ w,
                               const float* __restrict__ b, unsigned short* __restrict__ y){
  int n = blockIdx.x;
  int t = threadIdx.x;
  const float* xr = x + (size_t)n*PROJ;
  float v0 = xr[t], v1 = xr[t+256], v2 = xr[t+512];
  float s  = v0+v1+v2;
  float s2 = v0*v0 + v1*v1 + v2*v2;
  #pragma unroll
  for (int off = 32; off; off >>= 1){ s += __shfl_down(s, off); s2 += __shfl_down(s2, off); }
  __shared__ float rs[4], rs2[4];
  __shared__ float s_mean, s_rstd;
  int wid = t >> 6, lane = t & 63;
  if (lane == 0){ rs[wid] = s; rs2[wid] = s2; }
  __syncthreads();
  if (t == 0){
    float S  = rs[0]+rs[1]+rs[2]+rs[3];
    float S2 = rs2[0]+rs2[1]+rs2[2]+rs2[3];
    float m  = S * (1.f/768.f);
    float var = S2 * (1.f/768.f) - m*m;
    s_mean = m; s_rstd = rsqrtf(var + LN_EPS);
  }
  __syncthreads();
  float m = s_mean, r = s_rstd;
  unsigned short* yr = y + (size_t)n*PROJ;
  yr[t]     = f2bf((v0-m)*r*w[t]     + b[t]);
  yr[t+256] = f2bf((v1-m)*r*w[t+256] + b[t+256]);
  yr[t+512] = f2bf((v2-m)*r*w[t+512] + b[t+512]);
}

// ---------------- bf16 MFMA GEMM:  C[m,n] = sum_k A[m,k]*W[n,k]
template<int EPI>
__global__ __launch_bounds__(256)
void k_gemm_mfma(const unsigned short* __restrict__ A, int lda,
                 const unsigned short* __restrict__ W,
                 void* __restrict__ Cv, int ldc,
                 int M, int N, int K,
                 const float* __restrict__ bias,
                 const float* __restrict__ res, int ldres){
  __shared__ unsigned short As[128*32];
  __shared__ unsigned short Bs[128*32];
  const int bm = blockIdx.y*128, bn = blockIdx.x*128;
  const int tid = threadIdx.x;
  const int lane = tid & 63, wid = tid >> 6;
  const int wm = wid >> 1, wn = wid & 1;

  const int rowA0 = tid >> 2;
  const int c8 = (tid & 3) << 3;

  f32x4 acc[4][4];
  #pragma unroll
  for (int i=0;i<4;i++)
    #pragma unroll
    for (int j=0;j<4;j++) acc[i][j] = (f32x4){0.f,0.f,0.f,0.f};

  const size_t amr0 = (size_t)min(bm + rowA0,      M-1) * lda;
  const size_t amr1 = (size_t)min(bm + rowA0 + 64, M-1) * lda;
  const size_t wnr0 = (size_t)min(bn + rowA0,      N-1) * K;
  const size_t wnr1 = (size_t)min(bn + rowA0 + 64, N-1) * K;

  unsigned short* ldsA0 = &As[(wid*64)*8];
  unsigned short* ldsA1 = &As[(256 + wid*64)*8];
  unsigned short* ldsB0 = &Bs[(wid*64)*8];
  unsigned short* ldsB1 = &Bs[(256 + wid*64)*8];

  for (int k0 = 0; k0 < K; k0 += 32){
    __syncthreads();
    GLOAD16(A + amr0 + k0 + c8, ldsA0);
    GLOAD16(A + amr1 + k0 + c8, ldsA1);
    GLOAD16(W + wnr0 + k0 + c8, ldsB0);
    GLOAD16(W + wnr1 + k0 + c8, ldsB1);
    __syncthreads();

    bf16x8 af[4], bfr[4];
    const int kb8 = (lane >> 4) * 8;
    #pragma unroll
    for (int mi=0; mi<4; mi++){
      int r = wm*64 + mi*16 + (lane & 15);
      af[mi] = *(const bf16x8*)&As[r*32 + kb8];
    }
    #pragma unroll
    for (int ni=0; ni<4; ni++){
      int r = wn*64 + ni*16 + (lane & 15);
      bfr[ni] = *(const bf16x8*)&Bs[r*32 + kb8];
    }
    #pragma unroll
    for (int mi=0; mi<4; mi++)
      #pragma unroll
      for (int ni=0; ni<4; ni++)
        acc[mi][ni] = __builtin_amdgcn_mfma_f32_16x16x32_bf16(af[mi], bfr[ni], acc[mi][ni], 0,0,0);
  }

  const int mrow0 = bm + wm*64 + ((lane>>4)<<2);
  const int ncol0 = bn + wn*64 + (lane & 15);
  #pragma unroll
  for (int mi=0; mi<4; mi++){
    #pragma unroll
    for (int r=0; r<4; r++){
      int m = mrow0 + mi*16 + r;
      if (m >= M) continue;
      #pragma unroll
      for (int ni=0; ni<4; ni++){
        int n = ncol0 + ni*16;
        if (n >= N) continue;
        float v = acc[mi][ni][r];
        if (EPI == 0){
          ((unsigned short*)Cv)[(size_t)m*ldc + n] = f2bf(v);
        } else if (EPI == 1){
          ((float*)Cv)[(size_t)m*ldc + n] = elu_f(v + bias[n]);
        } else {
          ((float*)Cv)[(size_t)m*ldc + n] = elu_f(v + bias[n] + res[(size_t)m*ldres + n]);
        }
      }
    }
  }
}

// ---------------- attention coefficients (bf16 hlin, vectorized) ----------------
template<int H, int C>
__global__ void k_attn_coef(const unsigned short* __restrict__ hlin,
                            const float* __restrict__ a_src,
                            const float* __restrict__ a_dst,
                            float* __restrict__ als, float* __restrict__ ald){
  constexpr int CH = C/4;
  int n = blockIdx.x;
  int wid = threadIdx.x >> 6, lane = threadIdx.x & 63;
  float ss = 0.f, sd = 0.f;
  if (lane < CH){
    bf16x4 hv = *(const bf16x4*)(hlin + (size_t)n*H*C + wid*C + lane*4);
    float4 as_ = *(const float4*)&a_src[wid*C + lane*4];
    float4 ad_ = *(const float4*)&a_dst[wid*C + lane*4];
    float h0 = bf2f((unsigned short)hv.x), h1 = bf2f((unsigned short)hv.y);
    float h2 = bf2f((unsigned short)hv.z), h3 = bf2f((unsigned short)hv.w);
    ss = h0*as_.x + h1*as_.y + h2*as_.z + h3*as_.w;
    sd = h0*ad_.x + h1*ad_.y + h2*ad_.z + h3*ad_.w;
  }
  #pragma unroll
  for (int off = 32; off; off >>= 1){ ss += __shfl_down(ss, off); sd += __shfl_down(sd, off); }
  if (lane == 0){ als[n*H + wid] = ss; ald[n*H + wid] = sd; }
}

// ---------------- per-dst-node softmax + aggregate (wave-parallel) ----------------
template<int H, int C, bool CONCAT, bool DO_ELU>
__global__ __launch_bounds__(256)
void k_attn_agg(const unsigned short* __restrict__ hlin,
                const float* __restrict__ als, const float* __restrict__ ald,
                const int* __restrict__ indptr, const int* __restrict__ csr_src,
                const float* __restrict__ bias,
                void* __restrict__ outv, int ldo, int col0){
  constexpr int TOT = H*C;
  constexpr int CHUNKS = TOT/4;            // bf16x4 chunks
  constexpr int CPL = (CHUNKS + 63)/64;    // chunks per lane per wave
  int n = blockIdx.x;
  int tid = threadIdx.x;
  int wv = tid >> 6, lane = tid & 63;
  int beg = indptr[n], end = indptr[n+1];

  __shared__ float s_m[H], s_dinv[H], s_ald[H];
  __shared__ float s_red[4][TOT];

  // ---- stage 1: online softmax stats, wave w handles heads w, w+4, ...
  for (int h = wv; h < H; h += 4){
    float aldv = ald[n*H + h];
    float m = -1e30f, d = 0.f;
    for (int e = beg + lane; e < end; e += 64){
      int s = csr_src[e];
      float v = als[s*H + h] + aldv;
      v = v > 0.f ? v : 0.2f*v;
      if (v > m){ d *= expf(m - v); m = v; }
      d += expf(v - m);
    }
    #pragma unroll
    for (int off = 1; off < 64; off <<= 1){
      float mo = __shfl_xor(m, off);
      float dd = __shfl_xor(d, off);
      float mn = fmaxf(m, mo);
      d = d*expf(m - mn) + dd*expf(mo - mn);
      m = mn;
    }
    if (lane == 0){ s_m[h] = m; s_dinv[h] = 1.f/(d + 1e-16f); s_ald[h] = aldv; }
  }
  __syncthreads();

  // ---- stage 2: edge-parallel gather; wave wv owns edges beg+wv, beg+wv+4, ...
  f32x4 acc[CPL];
  #pragma unroll
  for (int p = 0; p < CPL; p++) acc[p] = (f32x4){0.f,0.f,0.f,0.f};

  for (int e = beg + wv; e < end; e += 4){
    int s = csr_src[e];
    const bf16x4* hr = (const bf16x4*)(hlin + (size_t)s*TOT);
    #pragma unroll
    for (int p = 0; p < CPL; p++){
      int ch = lane + p*64;
      if (CHUNKS % 64 == 0 || ch < CHUNKS){
        int h = (ch*4)/C;
        float v = als[s*H + h] + s_ald[h];
        v = v > 0.f ? v : 0.2f*v;
        float alpha = expf(v - s_m[h]) * s_dinv[h];
        bf16x4 hv = hr[ch];
        acc[p].x += bf2f((unsigned short)hv.x)*alpha;
        acc[p].y += bf2f((unsigned short)hv.y)*alpha;
        acc[p].z += bf2f((unsigned short)hv.z)*alpha;
        acc[p].w += bf2f((unsigned short)hv.w)*alpha;
      }
    }
  }

  #pragma unroll
  for (int p = 0; p < CPL; p++){
    int ch = lane + p*64;
    if (CHUNKS % 64 == 0 || ch < CHUNKS)
      *(f32x4*)&s_red[wv][ch*4] = acc[p];
  }
  __syncthreads();

  // ---- stage 3: cross-wave reduce + epilogue
  if (CONCAT){
    unsigned short* out = (unsigned short*)outv;
    constexpr int QS = (TOT + 255)/256;
    #pragma unroll
    for (int q = 0; q < QS; q++){
      int idx = tid + q*256;
      if (TOT % 256 == 0 || idx < TOT){
        float v = s_red[0][idx] + s_red[1][idx] + s_red[2][idx] + s_red[3][idx] + bias[idx];
        if (DO_ELU) v = elu_f(v);
        out[(size_t)n*ldo + col0 + idx] = f2bf(v);
      }
    }
  } else {
    float* out = (float*)outv;
    if (tid < C){
      float v = 0.f;
      #pragma unroll
      for (int h = 0; h < H; h++){
        int idx = h*C + tid;
        v += s_red[0][idx] + s_red[1][idx] + s_red[2][idx] + s_red[3][idx];
      }
      out[(size_t)n*ldo + tid] = v*(1.f/(float)H) + bias[tid];
    }
  }
}

// ---------------- launch ----------------
extern "C" void kernel_launch(void* const* d_in, const int* in_sizes, int n_in,
                              void* d_out, int out_size, void* d_ws, size_t ws_size,
                              hipStream_t stream){
  const float* x      = (const float*)d_in[0];
  const int*   ei     = (const int*)  d_in[1];
  const float* proj_W = (const float*)d_in[2];
  const float* proj_b = (const float*)d_in[3];
  const float* norm_w = (const float*)d_in[4];
  const float* norm_b = (const float*)d_in[5];
  const float* g1_W   = (const float*)d_in[6];
  const float* g1_as  = (const float*)d_in[7];
  const float* g1_ad  = (const float*)d_in[8];
  const float* g1_b   = (const float*)d_in[9];
  const float* g2_W   = (const float*)d_in[10];
  const float* g2_as  = (const float*)d_in[11];
  const float* g2_ad  = (const float*)d_in[12];
  const float* g2_b   = (const float*)d_in[13];
  const float* uni_W  = (const float*)d_in[14];
  const float* uni_b  = (const float*)d_in[15];
  const float* fnorm_w= (const float*)d_in[16];
  const float* fnorm_b= (const float*)d_in[17];
  const float* fg_W   = (const float*)d_in[18];
  const float* fg_as  = (const float*)d_in[19];
  const float* fg_ad  = (const float*)d_in[20];
  const float* fg_b   = (const float*)d_in[21];

  float* w = (float*)d_ws;
  float* h    = w; w += 7680000;
  float* h2   = w; w += 7680000;
  unsigned short* lin1 = (unsigned short*)w; w += 5120000;
  unsigned short* lin2 = (unsigned short*)w; w += 960000;
  unsigned short* hnb  = (unsigned short*)w; w += 3840000;
  unsigned short* catb = (unsigned short*)w; w += 4800000;
  unsigned short* wb   = (unsigned short*)w; w += 3489792;
  float* als  = w; w += 80000;
  float* ald  = w; w += 80000;
  int* iw = (int*)w;
  int* cnt     = iw; iw += 10016;
  int* indptr  = iw; iw += 10016;
  int* pos     = iw; iw += 10016;
  int* csr_src = iw; iw += 110016;

  unsigned short* wb_proj = wb;
  unsigned short* wb_g1   = wb_proj + 294912;
  unsigned short* wb_g2   = wb_g1 + 2359296;
  unsigned short* wb_uni  = wb_g2 + 589824;
  unsigned short* wb_fg   = wb_uni + 2949120;

  // CSR
  hipMemsetAsync(cnt, 0, N_NODES*sizeof(int), stream);
  k_count<<<(E_TOT+255)/256, 256, 0, stream>>>(ei, cnt);
  k_scan<<<1, 1024, 0, stream>>>(cnt, indptr);
  k_copy_int<<<(N_NODES+255)/256, 256, 0, stream>>>(indptr, pos, N_NODES);
  k_fill<<<(E_TOT+255)/256, 256, 0, stream>>>(ei, pos, csr_src);

  // fp32 -> bf16 converts (vectorized)
  k_f2bf_arr4<<<(960000+255)/256, 256, 0, stream>>>((const float4*)x, (ushort4*)hnb, 960000);
  k_f2bf_arr4<<<(73728+255)/256,  256, 0, stream>>>((const float4*)proj_W, (ushort4*)wb_proj, 73728);
  k_f2bf_arr4<<<(589824+255)/256, 256, 0, stream>>>((const float4*)g1_W, (ushort4*)wb_g1, 589824);
  k_f2bf_arr4<<<(147456+255)/256, 256, 0, stream>>>((const float4*)g2_W, (ushort4*)wb_g2, 147456);
  k_f2bf_arr4<<<(737280+255)/256, 256, 0, stream>>>((const float4*)uni_W, (ushort4*)wb_uni, 737280);
  k_f2bf_arr4<<<(196608+255)/256, 256, 0, stream>>>((const float4*)fg_W, (ushort4*)wb_fg, 196608);

  dim3 blk(256);
  const int GY = (N_NODES + 127) / 128;  // 79

  // h = elu(x @ proj_W.T + proj_b)
  k_gemm_mfma<1><<<dim3(6, GY), blk, 0, stream>>>(hnb, 384, wb_proj, h, 768, N_NODES, 768, 384, proj_b, nullptr, 0);

  float* cur = h;
  float* oth = h2;
  for (int i = 0; i < 4; i++){
    k_layernorm_bf<<<N_NODES, 256, 0, stream>>>(cur, norm_w + i*768, norm_b + i*768, hnb);
    k_gemm_mfma<0><<<dim3(6, GY), blk, 0, stream>>>(hnb, 768, wb_g1 + (size_t)i*589824, lin1, 768, N_NODES, 768, 768, nullptr, nullptr, 0);
    k_gemm_mfma<0><<<dim3(2, GY), blk, 0, stream>>>(hnb, 768, wb_g2 + (size_t)i*147456, lin2, 192, N_NODES, 192, 768, nullptr, nullptr, 0);
    k_attn_coef<4,192><<<N_NODES, 256, 0, stream>>>(lin1, g1_as + i*768, g1_ad + i*768, als, ald);
    k_attn_agg<4,192,true,true><<<N_NODES, 256, 0, stream>>>(lin1, als, ald, indptr, csr_src, g1_b + i*768, catb, 960, 0);
    k_attn_coef<2,96><<<N_NODES, 128, 0, stream>>>(lin2, g2_as + i*192, g2_ad + i*192, als, ald);
    k_attn_agg<2,96,true,true><<<N_NODES, 256, 0, stream>>>(lin2, als, ald, indptr, csr_src, g2_b + i*192, catb, 960, 768);
    k_gemm_mfma<2><<<dim3(6, GY), blk, 0, stream>>>(catb, 960, wb_uni + (size_t)i*737280, oth, 768, N_NODES, 768, 960, uni_b + i*768, cur, 768);
    float* t = cur; cur = oth; oth = t;
  }

  k_layernorm_bf<<<N_NODES, 256, 0, stream>>>(cur, fnorm_w, fnorm_b, hnb);
  k_gemm_mfma<0><<<dim3(8, GY), blk, 0, stream>>>(hnb, 768, wb_fg, lin1, 1024, N_NODES, 1024, 768, nullptr, nullptr, 0);
  k_attn_coef<8,128><<<N_NODES, 512, 0, stream>>>(lin1, fg_as, fg_ad, als, ald);
  k_attn_agg<8,128,false,false><<<N_NODES, 256, 0, stream>>>(lin1, als, ald, indptr, csr_src, fg_b, d_out, 128, 0);
}

// Round 4
// 835.872 us; speedup vs baseline: 3.5891x; 1.1691x over previous
//
#include <hip/hip_runtime.h>
#include <math.h>

#define N_NODES 10000
#define N_EDGES 100000
#define E_TOT   (N_EDGES + N_NODES)
#define PROJ    768
#define LN_EPS  1e-5f

typedef __attribute__((ext_vector_type(8))) short bf16x8;
typedef __attribute__((ext_vector_type(4))) short bf16x4;
typedef __attribute__((ext_vector_type(4))) float f32x4;

__device__ __forceinline__ float elu_f(float x){ return x > 0.f ? x : __expf(x) - 1.f; }
__device__ __forceinline__ float bf2f(unsigned short u){ return __uint_as_float(((unsigned int)u) << 16); }
__device__ __forceinline__ unsigned short f2bf(float f){
  unsigned int u = __float_as_uint(f);
  return (unsigned short)((u + 0x7FFFu + ((u >> 16) & 1u)) >> 16);
}

#define GLOAD16(gp, lp) __builtin_amdgcn_global_load_lds((const __attribute__((address_space(1))) void*)(gp), (__attribute__((address_space(3))) void*)(lp), 16, 0, 0)

// ---------------- CSR build (by dst, self loops appended) ----------------
__global__ void k_count(const int* __restrict__ ei, int* __restrict__ cnt){
  int e = blockIdx.x*blockDim.x + threadIdx.x;
  if (e >= E_TOT) return;
  int dst = (e < N_EDGES) ? ei[N_EDGES + e] : (e - N_EDGES);
  atomicAdd(&cnt[dst], 1);
}

__global__ void k_scan(const int* __restrict__ cnt, int* __restrict__ indptr){
  __shared__ int s[1024];
  __shared__ int s_running;
  int t = threadIdx.x;
  if (t == 0) s_running = 0;
  __syncthreads();
  for (int base = 0; base < N_NODES; base += 1024){
    int v = (base + t < N_NODES) ? cnt[base + t] : 0;
    s[t] = v; __syncthreads();
    for (int off = 1; off < 1024; off <<= 1){
      int add = (t >= off) ? s[t - off] : 0;
      __syncthreads();
      s[t] += add;
      __syncthreads();
    }
    int total = s[1023];
    int run = s_running;
    if (base + t < N_NODES) indptr[base + t] = run + s[t] - v;
    __syncthreads();
    if (t == 0) s_running = run + total;
    __syncthreads();
  }
  if (t == 0) indptr[N_NODES] = s_running;
}

__global__ void k_copy_int(const int* __restrict__ src, int* __restrict__ dst, int n){
  int i = blockIdx.x*blockDim.x + threadIdx.x;
  if (i < n) dst[i] = src[i];
}

__global__ void k_fill(const int* __restrict__ ei, int* __restrict__ pos, int* __restrict__ csr_src){
  int e = blockIdx.x*blockDim.x + threadIdx.x;
  if (e >= E_TOT) return;
  int s, d;
  if (e < N_EDGES){ s = ei[e]; d = ei[N_EDGES + e]; }
  else            { s = d = e - N_EDGES; }
  int p = atomicAdd(&pos[d], 1);
  csr_src[p] = s;
}

__global__ void k_f2bf_arr4(const float4* __restrict__ in, ushort4* __restrict__ out, int n4){
  int i = blockIdx.x*blockDim.x + threadIdx.x;
  if (i < n4){
    float4 v = in[i];
    ushort4 o;
    o.x = f2bf(v.x); o.y = f2bf(v.y); o.z = f2bf(v.z); o.w = f2bf(v.w);
    out[i] = o;
  }
}

// pack g1_W[4][768][768] + g2_W[4][192][768] -> per-layer [960][768] bf16
__global__ void k_pack_l1l2(const float* __restrict__ g1, const float* __restrict__ g2,
                            unsigned short* __restrict__ dst){
  int i = blockIdx.x*blockDim.x + threadIdx.x;   // float4 units, total 4*184320
  if (i >= 737280) return;
  int layer = i / 184320;
  int off4  = i - layer*184320;
  float4 v;
  if (off4 < 147456) v = *((const float4*)(g1 + (size_t)layer*589824) + off4);
  else               v = *((const float4*)(g2 + (size_t)layer*147456) + (off4 - 147456));
  ushort4 o;
  o.x = f2bf(v.x); o.y = f2bf(v.y); o.z = f2bf(v.z); o.w = f2bf(v.w);
  ((ushort4*)(dst + (size_t)layer*737280))[off4] = o;
}

// ---------------- LayerNorm over 768 -> bf16 output ----------------
__global__ void k_layernorm_bf(const float* __restrict__ x, const float* __restrict__ w,
                               const float* __restrict__ b, unsigned short* __restrict__ y){
  int n = blockIdx.x;
  int t = threadIdx.x;
  const float* xr = x + (size_t)n*PROJ;
  float v0 = xr[t], v1 = xr[t+256], v2 = xr[t+512];
  float s  = v0+v1+v2;
  float s2 = v0*v0 + v1*v1 + v2*v2;
  #pragma unroll
  for (int off = 32; off; off >>= 1){ s += __shfl_down(s, off); s2 += __shfl_down(s2, off); }
  __shared__ float rs[4], rs2[4];
  __shared__ float s_mean, s_rstd;
  int wid = t >> 6, lane = t & 63;
  if (lane == 0){ rs[wid] = s; rs2[wid] = s2; }
  __syncthreads();
  if (t == 0){
    float S  = rs[0]+rs[1]+rs[2]+rs[3];
    float S2 = rs2[0]+rs2[1]+rs2[2]+rs2[3];
    float m  = S * (1.f/768.f);
    float var = S2 * (1.f/768.f) - m*m;
    s_mean = m; s_rstd = rsqrtf(var + LN_EPS);
  }
  __syncthreads();
  float m = s_mean, r = s_rstd;
  unsigned short* yr = y + (size_t)n*PROJ;
  yr[t]     = f2bf((v0-m)*r*w[t]     + b[t]);
  yr[t+256] = f2bf((v1-m)*r*w[t+256] + b[t+256]);
  yr[t+512] = f2bf((v2-m)*r*w[t+512] + b[t+512]);
}

// ---------------- bf16 MFMA GEMM:  C[m,n] = sum_k A[m,k]*W[n,k]
template<int EPI>
__global__ __launch_bounds__(256)
void k_gemm_mfma(const unsigned short* __restrict__ A, int lda,
                 const unsigned short* __restrict__ W,
                 void* __restrict__ Cv, int ldc,
                 int M, int N, int K,
                 const float* __restrict__ bias,
                 const float* __restrict__ res, int ldres){
  __shared__ unsigned short As[128*32];
  __shared__ unsigned short Bs[128*32];
  const int bm = blockIdx.y*128, bn = blockIdx.x*128;
  const int tid = threadIdx.x;
  const int lane = tid & 63, wid = tid >> 6;
  const int wm = wid >> 1, wn = wid & 1;

  const int rowA0 = tid >> 2;
  const int c8 = (tid & 3) << 3;

  f32x4 acc[4][4];
  #pragma unroll
  for (int i=0;i<4;i++)
    #pragma unroll
    for (int j=0;j<4;j++) acc[i][j] = (f32x4){0.f,0.f,0.f,0.f};

  const size_t amr0 = (size_t)min(bm + rowA0,      M-1) * lda;
  const size_t amr1 = (size_t)min(bm + rowA0 + 64, M-1) * lda;
  const size_t wnr0 = (size_t)min(bn + rowA0,      N-1) * K;
  const size_t wnr1 = (size_t)min(bn + rowA0 + 64, N-1) * K;

  unsigned short* ldsA0 = &As[(wid*64)*8];
  unsigned short* ldsA1 = &As[(256 + wid*64)*8];
  unsigned short* ldsB0 = &Bs[(wid*64)*8];
  unsigned short* ldsB1 = &Bs[(256 + wid*64)*8];

  for (int k0 = 0; k0 < K; k0 += 32){
    __syncthreads();
    GLOAD16(A + amr0 + k0 + c8, ldsA0);
    GLOAD16(A + amr1 + k0 + c8, ldsA1);
    GLOAD16(W + wnr0 + k0 + c8, ldsB0);
    GLOAD16(W + wnr1 + k0 + c8, ldsB1);
    __syncthreads();

    bf16x8 af[4], bfr[4];
    const int kb8 = (lane >> 4) * 8;
    #pragma unroll
    for (int mi=0; mi<4; mi++){
      int r = wm*64 + mi*16 + (lane & 15);
      af[mi] = *(const bf16x8*)&As[r*32 + kb8];
    }
    #pragma unroll
    for (int ni=0; ni<4; ni++){
      int r = wn*64 + ni*16 + (lane & 15);
      bfr[ni] = *(const bf16x8*)&Bs[r*32 + kb8];
    }
    #pragma unroll
    for (int mi=0; mi<4; mi++)
      #pragma unroll
      for (int ni=0; ni<4; ni++)
        acc[mi][ni] = __builtin_amdgcn_mfma_f32_16x16x32_bf16(af[mi], bfr[ni], acc[mi][ni], 0,0,0);
  }

  const int mrow0 = bm + wm*64 + ((lane>>4)<<2);
  const int ncol0 = bn + wn*64 + (lane & 15);
  #pragma unroll
  for (int mi=0; mi<4; mi++){
    #pragma unroll
    for (int r=0; r<4; r++){
      int m = mrow0 + mi*16 + r;
      if (m >= M) continue;
      #pragma unroll
      for (int ni=0; ni<4; ni++){
        int n = ncol0 + ni*16;
        if (n >= N) continue;
        float v = acc[mi][ni][r];
        if (EPI == 0){
          ((unsigned short*)Cv)[(size_t)m*ldc + n] = f2bf(v);
        } else if (EPI == 1){
          ((float*)Cv)[(size_t)m*ldc + n] = elu_f(v + bias[n]);
        } else {
          ((float*)Cv)[(size_t)m*ldc + n] = elu_f(v + bias[n] + res[(size_t)m*ldres + n]);
        }
      }
    }
  }
}

// ---------------- attention coefficients (bf16 hlin, vectorized) ----------------
template<int H, int C>
__global__ void k_attn_coef(const unsigned short* __restrict__ hlin, int ldh,
                            const float* __restrict__ a_src,
                            const float* __restrict__ a_dst,
                            float* __restrict__ als, float* __restrict__ ald){
  constexpr int CH = C/4;
  int n = blockIdx.x;
  int wid = threadIdx.x >> 6, lane = threadIdx.x & 63;
  float ss = 0.f, sd = 0.f;
  if (lane < CH){
    bf16x4 hv = *(const bf16x4*)(hlin + (size_t)n*ldh + wid*C + lane*4);
    float4 as_ = *(const float4*)&a_src[wid*C + lane*4];
    float4 ad_ = *(const float4*)&a_dst[wid*C + lane*4];
    float h0 = bf2f((unsigned short)hv.x), h1 = bf2f((unsigned short)hv.y);
    float h2 = bf2f((unsigned short)hv.z), h3 = bf2f((unsigned short)hv.w);
    ss = h0*as_.x + h1*as_.y + h2*as_.z + h3*as_.w;
    sd = h0*ad_.x + h1*ad_.y + h2*ad_.z + h3*ad_.w;
  }
  #pragma unroll
  for (int off = 32; off; off >>= 1){ ss += __shfl_down(ss, off); sd += __shfl_down(sd, off); }
  if (lane == 0){ als[n*H + wid] = ss; ald[n*H + wid] = sd; }
}

// ---------------- per-dst-node softmax + aggregate (wave-parallel) ----------------
template<int H, int C, bool CONCAT, bool DO_ELU>
__global__ __launch_bounds__(256)
void k_attn_agg(const unsigned short* __restrict__ hlin, int ldh,
                const float* __restrict__ als, const float* __restrict__ ald,
                const int* __restrict__ indptr, const int* __restrict__ csr_src,
                const float* __restrict__ bias,
                void* __restrict__ outv, int ldo, int col0){
  constexpr int TOT = H*C;
  constexpr int CHUNKS = TOT/4;
  constexpr int CPL = (CHUNKS + 63)/64;
  int n = blockIdx.x;
  int tid = threadIdx.x;
  int wv = tid >> 6, lane = tid & 63;
  int beg = indptr[n], end = indptr[n+1];

  __shared__ float s_m[H], s_dinv[H], s_ald[H];
  __shared__ float s_red[4][TOT];

  // ---- stage 1: online softmax stats, wave w handles heads w, w+4, ...
  for (int h = wv; h < H; h += 4){
    float aldv = ald[n*H + h];
    float m = -1e30f, d = 0.f;
    for (int e = beg + lane; e < end; e += 64){
      int s = csr_src[e];
      float v = als[s*H + h] + aldv;
      v = v > 0.f ? v : 0.2f*v;
      if (v > m){ d *= __expf(m - v); m = v; }
      d += __expf(v - m);
    }
    #pragma unroll
    for (int off = 1; off < 64; off <<= 1){
      float mo = __shfl_xor(m, off);
      float dd = __shfl_xor(d, off);
      float mn = fmaxf(m, mo);
      d = d*__expf(m - mn) + dd*__expf(mo - mn);
      m = mn;
    }
    if (lane == 0){ s_m[h] = m; s_dinv[h] = 1.f/(d + 1e-16f); s_ald[h] = aldv; }
  }
  __syncthreads();

  // ---- stage 2: edge-parallel gather; wave wv owns edges beg+wv, beg+wv+4, ...
  int hof[CPL];
  #pragma unroll
  for (int p = 0; p < CPL; p++) hof[p] = ((lane + p*64)*4)/C;

  f32x4 acc[CPL];
  #pragma unroll
  for (int p = 0; p < CPL; p++) acc[p] = (f32x4){0.f,0.f,0.f,0.f};

  for (int e = beg + wv; e < end; e += 4){
    int s = csr_src[e];
    float al = 0.f;
    if (lane < H){
      float v = als[s*H + lane] + s_ald[lane];
      v = v > 0.f ? v : 0.2f*v;
      al = __expf(v - s_m[lane]) * s_dinv[lane];
    }
    float aph[CPL];
    #pragma unroll
    for (int p = 0; p < CPL; p++) aph[p] = __shfl(al, hof[p]);
    const bf16x4* hr = (const bf16x4*)(hlin + (size_t)s*ldh);
    #pragma unroll
    for (int p = 0; p < CPL; p++){
      int ch = lane + p*64;
      if (CHUNKS % 64 == 0 || ch < CHUNKS){
        bf16x4 hv = hr[ch];
        acc[p].x += bf2f((unsigned short)hv.x)*aph[p];
        acc[p].y += bf2f((unsigned short)hv.y)*aph[p];
        acc[p].z += bf2f((unsigned short)hv.z)*aph[p];
        acc[p].w += bf2f((unsigned short)hv.w)*aph[p];
      }
    }
  }

  #pragma unroll
  for (int p = 0; p < CPL; p++){
    int ch = lane + p*64;
    if (CHUNKS % 64 == 0 || ch < CHUNKS)
      *(f32x4*)&s_red[wv][ch*4] = acc[p];
  }
  __syncthreads();

  // ---- stage 3: cross-wave reduce + epilogue
  if (CONCAT){
    unsigned short* out = (unsigned short*)outv;
    constexpr int QS = (TOT + 255)/256;
    #pragma unroll
    for (int q = 0; q < QS; q++){
      int idx = tid + q*256;
      if (TOT % 256 == 0 || idx < TOT){
        float v = s_red[0][idx] + s_red[1][idx] + s_red[2][idx] + s_red[3][idx] + bias[idx];
        if (DO_ELU) v = elu_f(v);
        out[(size_t)n*ldo + col0 + idx] = f2bf(v);
      }
    }
  } else {
    float* out = (float*)outv;
    if (tid < C){
      float v = 0.f;
      #pragma unroll
      for (int h = 0; h < H; h++){
        int idx = h*C + tid;
        v += s_red[0][idx] + s_red[1][idx] + s_red[2][idx] + s_red[3][idx];
      }
      out[(size_t)n*ldo + tid] = v*(1.f/(float)H) + bias[tid];
    }
  }
}

// ---------------- launch ----------------
extern "C" void kernel_launch(void* const* d_in, const int* in_sizes, int n_in,
                              void* d_out, int out_size, void* d_ws, size_t ws_size,
                              hipStream_t stream){
  const float* x      = (const float*)d_in[0];
  const int*   ei     = (const int*)  d_in[1];
  const float* proj_W = (const float*)d_in[2];
  const float* proj_b = (const float*)d_in[3];
  const float* norm_w = (const float*)d_in[4];
  const float* norm_b = (const float*)d_in[5];
  const float* g1_W   = (const float*)d_in[6];
  const float* g1_as  = (const float*)d_in[7];
  const float* g1_ad  = (const float*)d_in[8];
  const float* g1_b   = (const float*)d_in[9];
  const float* g2_W   = (const float*)d_in[10];
  const float* g2_as  = (const float*)d_in[11];
  const float* g2_ad  = (const float*)d_in[12];
  const float* g2_b   = (const float*)d_in[13];
  const float* uni_W  = (const float*)d_in[14];
  const float* uni_b  = (const float*)d_in[15];
  const float* fnorm_w= (const float*)d_in[16];
  const float* fnorm_b= (const float*)d_in[17];
  const float* fg_W   = (const float*)d_in[18];
  const float* fg_as  = (const float*)d_in[19];
  const float* fg_ad  = (const float*)d_in[20];
  const float* fg_b   = (const float*)d_in[21];

  float* w = (float*)d_ws;
  float* h    = w; w += 7680000;
  float* h2   = w; w += 7680000;
  unsigned short* linbuf = (unsigned short*)w; w += 5120000;  // bf16 [10000,1024] / [10000,960]
  unsigned short* hnb  = (unsigned short*)w; w += 3840000;
  unsigned short* catb = (unsigned short*)w; w += 4800000;
  unsigned short* wb   = (unsigned short*)w; w += 3489792;
  float* als  = w; w += 80000;
  float* ald  = w; w += 80000;
  float* als2 = w; w += 80000;
  float* ald2 = w; w += 80000;
  int* iw = (int*)w;
  int* cnt     = iw; iw += 10016;
  int* indptr  = iw; iw += 10016;
  int* pos     = iw; iw += 10016;
  int* csr_src = iw; iw += 110016;

  unsigned short* wb_proj = wb;
  unsigned short* wb_l12  = wb_proj + 294912;   // 4 x [960][768]
  unsigned short* wb_uni  = wb_l12 + 2949120;
  unsigned short* wb_fg   = wb_uni + 2949120;

  // CSR
  hipMemsetAsync(cnt, 0, N_NODES*sizeof(int), stream);
  k_count<<<(E_TOT+255)/256, 256, 0, stream>>>(ei, cnt);
  k_scan<<<1, 1024, 0, stream>>>(cnt, indptr);
  k_copy_int<<<(N_NODES+255)/256, 256, 0, stream>>>(indptr, pos, N_NODES);
  k_fill<<<(E_TOT+255)/256, 256, 0, stream>>>(ei, pos, csr_src);

  // fp32 -> bf16 converts (vectorized)
  k_f2bf_arr4<<<(960000+255)/256, 256, 0, stream>>>((const float4*)x, (ushort4*)hnb, 960000);
  k_f2bf_arr4<<<(73728+255)/256,  256, 0, stream>>>((const float4*)proj_W, (ushort4*)wb_proj, 73728);
  k_pack_l1l2<<<(737280+255)/256, 256, 0, stream>>>(g1_W, g2_W, wb_l12);
  k_f2bf_arr4<<<(737280+255)/256, 256, 0, stream>>>((const float4*)uni_W, (ushort4*)wb_uni, 737280);
  k_f2bf_arr4<<<(196608+255)/256, 256, 0, stream>>>((const float4*)fg_W, (ushort4*)wb_fg, 196608);

  dim3 blk(256);
  const int GY = (N_NODES + 127) / 128;  // 79

  // h = elu(x @ proj_W.T + proj_b)
  k_gemm_mfma<1><<<dim3(6, GY), blk, 0, stream>>>(hnb, 384, wb_proj, h, 768, N_NODES, 768, 384, proj_b, nullptr, 0);

  float* cur = h;
  float* oth = h2;
  for (int i = 0; i < 4; i++){
    k_layernorm_bf<<<N_NODES, 256, 0, stream>>>(cur, norm_w + i*768, norm_b + i*768, hnb);
    // combined [g1 | g2] GEMM: N = 960
    k_gemm_mfma<0><<<dim3(8, GY), blk, 0, stream>>>(hnb, 768, wb_l12 + (size_t)i*737280, linbuf, 960, N_NODES, 960, 768, nullptr, nullptr, 0);
    k_attn_coef<4,192><<<N_NODES, 256, 0, stream>>>(linbuf, 960, g1_as + i*768, g1_ad + i*768, als, ald);
    k_attn_agg<4,192,true,true><<<N_NODES, 256, 0, stream>>>(linbuf, 960, als, ald, indptr, csr_src, g1_b + i*768, catb, 960, 0);
    k_attn_coef<2,96><<<N_NODES, 128, 0, stream>>>(linbuf + 768, 960, g2_as + i*192, g2_ad + i*192, als2, ald2);
    k_attn_agg<2,96,true,true><<<N_NODES, 256, 0, stream>>>(linbuf + 768, 960, als2, ald2, indptr, csr_src, g2_b + i*192, catb, 960, 768);
    k_gemm_mfma<2><<<dim3(6, GY), blk, 0, stream>>>(catb, 960, wb_uni + (size_t)i*737280, oth, 768, N_NODES, 768, 960, uni_b + i*768, cur, 768);
    float* t = cur; cur = oth; oth = t;
  }

  k_layernorm_bf<<<N_NODES, 256, 0, stream>>>(cur, fnorm_w, fnorm_b, hnb);
  k_gemm_mfma<0><<<dim3(8, GY), blk, 0, stream>>>(hnb, 768, wb_fg, linbuf, 1024, N_NODES, 1024, 768, nullptr, nullptr, 0);
  k_attn_coef<8,128><<<N_NODES, 512, 0, stream>>>(linbuf, 1024, fg_as, fg_ad, als, ald);
  k_attn_agg<8,128,false,false><<<N_NODES, 256, 0, stream>>>(linbuf, 1024, als, ald, indptr, csr_src, fg_b, d_out, 128, 0);
}

// Round 5
// 789.561 us; speedup vs baseline: 3.7996x; 1.0587x over previous
//
#include <hip/hip_runtime.h>
#include <math.h>

#define N_NODES 10000
#define N_EDGES 100000
#define E_TOT   (N_EDGES + N_NODES)
#define PROJ    768
#define LN_EPS  1e-5f

typedef __attribute__((ext_vector_type(8))) short bf16x8;
typedef __attribute__((ext_vector_type(4))) short bf16x4;
typedef __attribute__((ext_vector_type(4))) float f32x4;

__device__ __forceinline__ float elu_f(float x){ return x > 0.f ? x : __expf(x) - 1.f; }
__device__ __forceinline__ float bf2f(unsigned short u){ return __uint_as_float(((unsigned int)u) << 16); }
__device__ __forceinline__ unsigned short f2bf(float f){
  unsigned int u = __float_as_uint(f);
  return (unsigned short)((u + 0x7FFFu + ((u >> 16) & 1u)) >> 16);
}

#define GLOAD16(gp, lp) __builtin_amdgcn_global_load_lds((const __attribute__((address_space(1))) void*)(gp), (__attribute__((address_space(3))) void*)(lp), 16, 0, 0)

// ---------------- CSR build (by dst, self loops appended) ----------------
__global__ void k_count(const int* __restrict__ ei, int* __restrict__ cnt){
  int e = blockIdx.x*blockDim.x + threadIdx.x;
  if (e >= E_TOT) return;
  int dst = (e < N_EDGES) ? ei[N_EDGES + e] : (e - N_EDGES);
  atomicAdd(&cnt[dst], 1);
}

__global__ void k_scan(const int* __restrict__ cnt, int* __restrict__ indptr){
  __shared__ int s[1024];
  __shared__ int s_running;
  int t = threadIdx.x;
  if (t == 0) s_running = 0;
  __syncthreads();
  for (int base = 0; base < N_NODES; base += 1024){
    int v = (base + t < N_NODES) ? cnt[base + t] : 0;
    s[t] = v; __syncthreads();
    for (int off = 1; off < 1024; off <<= 1){
      int add = (t >= off) ? s[t - off] : 0;
      __syncthreads();
      s[t] += add;
      __syncthreads();
    }
    int total = s[1023];
    int run = s_running;
    if (base + t < N_NODES) indptr[base + t] = run + s[t] - v;
    __syncthreads();
    if (t == 0) s_running = run + total;
    __syncthreads();
  }
  if (t == 0) indptr[N_NODES] = s_running;
}

__global__ void k_copy_int(const int* __restrict__ src, int* __restrict__ dst, int n){
  int i = blockIdx.x*blockDim.x + threadIdx.x;
  if (i < n) dst[i] = src[i];
}

__global__ void k_fill(const int* __restrict__ ei, int* __restrict__ pos, int* __restrict__ csr_src){
  int e = blockIdx.x*blockDim.x + threadIdx.x;
  if (e >= E_TOT) return;
  int s, d;
  if (e < N_EDGES){ s = ei[e]; d = ei[N_EDGES + e]; }
  else            { s = d = e - N_EDGES; }
  int p = atomicAdd(&pos[d], 1);
  csr_src[p] = s;
}

__global__ void k_f2bf_arr4(const float4* __restrict__ in, ushort4* __restrict__ out, int n4){
  int i = blockIdx.x*blockDim.x + threadIdx.x;
  if (i < n4){
    float4 v = in[i];
    ushort4 o;
    o.x = f2bf(v.x); o.y = f2bf(v.y); o.z = f2bf(v.z); o.w = f2bf(v.w);
    out[i] = o;
  }
}

// pack g1_W[4][768][768] + g2_W[4][192][768] -> per-layer [960][768] bf16
__global__ void k_pack_l1l2(const float* __restrict__ g1, const float* __restrict__ g2,
                            unsigned short* __restrict__ dst){
  int i = blockIdx.x*blockDim.x + threadIdx.x;
  if (i >= 737280) return;
  int layer = i / 184320;
  int off4  = i - layer*184320;
  float4 v;
  if (off4 < 147456) v = *((const float4*)(g1 + (size_t)layer*589824) + off4);
  else               v = *((const float4*)(g2 + (size_t)layer*147456) + (off4 - 147456));
  ushort4 o;
  o.x = f2bf(v.x); o.y = f2bf(v.y); o.z = f2bf(v.z); o.w = f2bf(v.w);
  ((ushort4*)(dst + (size_t)layer*737280))[off4] = o;
}

// ---------------- LayerNorm over 768 -> bf16 output ----------------
__global__ void k_layernorm_bf(const float* __restrict__ x, const float* __restrict__ w,
                               const float* __restrict__ b, unsigned short* __restrict__ y){
  int n = blockIdx.x;
  int t = threadIdx.x;
  const float* xr = x + (size_t)n*PROJ;
  float v0 = xr[t], v1 = xr[t+256], v2 = xr[t+512];
  float s  = v0+v1+v2;
  float s2 = v0*v0 + v1*v1 + v2*v2;
  #pragma unroll
  for (int off = 32; off; off >>= 1){ s += __shfl_down(s, off); s2 += __shfl_down(s2, off); }
  __shared__ float rs[4], rs2[4];
  __shared__ float s_mean, s_rstd;
  int wid = t >> 6, lane = t & 63;
  if (lane == 0){ rs[wid] = s; rs2[wid] = s2; }
  __syncthreads();
  if (t == 0){
    float S  = rs[0]+rs[1]+rs[2]+rs[3];
    float S2 = rs2[0]+rs2[1]+rs2[2]+rs2[3];
    float m  = S * (1.f/768.f);
    float var = S2 * (1.f/768.f) - m*m;
    s_mean = m; s_rstd = rsqrtf(var + LN_EPS);
  }
  __syncthreads();
  float m = s_mean, r = s_rstd;
  unsigned short* yr = y + (size_t)n*PROJ;
  yr[t]     = f2bf((v0-m)*r*w[t]     + b[t]);
  yr[t+256] = f2bf((v1-m)*r*w[t+256] + b[t+256]);
  yr[t+512] = f2bf((v2-m)*r*w[t+512] + b[t+512]);
}

// ---------------- bf16 MFMA GEMM, 2-phase dbuf, BK=64, XOR-swizzled LDS ----------------
// C[m,n] = sum_k A[m,k]*W[n,k]; EPI 0: bf16 out; 1: f32 elu(v+bias); 2: f32 elu(v+bias+res)
template<int EPI>
__global__ __launch_bounds__(256, 2)
void k_gemm_mfma(const unsigned short* __restrict__ A, int lda,
                 const unsigned short* __restrict__ W,
                 void* __restrict__ Cv, int ldc,
                 int M, int N, int K,
                 const float* __restrict__ bias,
                 const float* __restrict__ res, int ldres, int NBN){
  __shared__ unsigned short As[2][128*64];
  __shared__ unsigned short Bs[2][128*64];
  const int tid = threadIdx.x;
  const int lane = tid & 63, wid = tid >> 6;
  const int wm = wid >> 1, wn = wid & 1;

  // bijective XCD remap (m204): contiguous bm stripes per XCD -> W panel L2-resident
  const int nwg = gridDim.x;
  const int q = nwg >> 3, r = nwg & 7;
  const int xcd = blockIdx.x & 7, o = blockIdx.x >> 3;
  const int swz = (xcd < r ? xcd*(q+1) : r*(q+1) + (xcd - r)*q) + o;
  const int bm = (swz / NBN) * 128;
  const int bn = (swz % NBN) * 128;

  // staging: pass p covers rows p*32..p*32+31; thread -> (row, c16 slot tid&7)
  // pre-swizzled global source col so that linear LDS dest == swizzled layout
  const int srow = tid >> 3;
  const int sc16 = (tid & 7) ^ (srow & 7);
  size_t ga[4], gb[4];
  #pragma unroll
  for (int p = 0; p < 4; p++){
    ga[p] = (size_t)min(bm + p*32 + srow, M-1)*lda + sc16*8;
    gb[p] = (size_t)min(bn + p*32 + srow, N-1)*K   + sc16*8;
  }
  const int ldst = tid*8;

  f32x4 acc[4][4];
  #pragma unroll
  for (int i=0;i<4;i++)
    #pragma unroll
    for (int j=0;j<4;j++) acc[i][j] = (f32x4){0.f,0.f,0.f,0.f};

  const int rA = wm*64 + (lane & 15);
  const int rB = wn*64 + (lane & 15);

  const int NT = K >> 6;
  int cur = 0;
  // prologue stage
  #pragma unroll
  for (int p = 0; p < 4; p++){
    GLOAD16(A + ga[p], &As[0][p*2048 + ldst]);
    GLOAD16(W + gb[p], &Bs[0][p*2048 + ldst]);
  }
  for (int t = 0; t < NT; ++t){
    __syncthreads();               // full drain: buf[cur] ready, prev reads done
    if (t + 1 < NT){
      const int k0 = (t+1) << 6;
      #pragma unroll
      for (int p = 0; p < 4; p++){
        GLOAD16(A + ga[p] + k0, &As[cur^1][p*2048 + ldst]);
        GLOAD16(W + gb[p] + k0, &Bs[cur^1][p*2048 + ldst]);
      }
    }
    #pragma unroll
    for (int kk = 0; kk < 2; kk++){
      bf16x8 af[4], bfr[4];
      const int cA = (((kk<<2) | (lane>>4)) ^ (lane&7)) * 8;
      #pragma unroll
      for (int mi = 0; mi < 4; mi++)
        af[mi] = *(const bf16x8*)&As[cur][(rA + mi*16)*64 + cA];
      #pragma unroll
      for (int ni = 0; ni < 4; ni++)
        bfr[ni] = *(const bf16x8*)&Bs[cur][(rB + ni*16)*64 + cA];
      #pragma unroll
      for (int mi = 0; mi < 4; mi++)
        #pragma unroll
        for (int ni = 0; ni < 4; ni++)
          acc[mi][ni] = __builtin_amdgcn_mfma_f32_16x16x32_bf16(af[mi], bfr[ni], acc[mi][ni], 0,0,0);
    }
    cur ^= 1;
  }

  const int mrow0 = bm + wm*64 + ((lane>>4)<<2);
  const int ncol0 = bn + wn*64 + (lane & 15);
  #pragma unroll
  for (int mi=0; mi<4; mi++){
    #pragma unroll
    for (int rr=0; rr<4; rr++){
      int m = mrow0 + mi*16 + rr;
      if (m >= M) continue;
      #pragma unroll
      for (int ni=0; ni<4; ni++){
        int n = ncol0 + ni*16;
        if (n >= N) continue;
        float v = acc[mi][ni][rr];
        if (EPI == 0){
          ((unsigned short*)Cv)[(size_t)m*ldc + n] = f2bf(v);
        } else if (EPI == 1){
          ((float*)Cv)[(size_t)m*ldc + n] = elu_f(v + bias[n]);
        } else {
          ((float*)Cv)[(size_t)m*ldc + n] = elu_f(v + bias[n] + res[(size_t)m*ldres + n]);
        }
      }
    }
  }
}

// ---------------- attention coefficients (bf16 hlin, vectorized) ----------------
template<int H, int C>
__global__ void k_attn_coef(const unsigned short* __restrict__ hlin, int ldh,
                            const float* __restrict__ a_src,
                            const float* __restrict__ a_dst,
                            float* __restrict__ als, float* __restrict__ ald){
  constexpr int CH = C/4;
  int n = blockIdx.x;
  int wid = threadIdx.x >> 6, lane = threadIdx.x & 63;
  float ss = 0.f, sd = 0.f;
  if (lane < CH){
    bf16x4 hv = *(const bf16x4*)(hlin + (size_t)n*ldh + wid*C + lane*4);
    float4 as_ = *(const float4*)&a_src[wid*C + lane*4];
    float4 ad_ = *(const float4*)&a_dst[wid*C + lane*4];
    float h0 = bf2f((unsigned short)hv.x), h1 = bf2f((unsigned short)hv.y);
    float h2 = bf2f((unsigned short)hv.z), h3 = bf2f((unsigned short)hv.w);
    ss = h0*as_.x + h1*as_.y + h2*as_.z + h3*as_.w;
    sd = h0*ad_.x + h1*ad_.y + h2*ad_.z + h3*ad_.w;
  }
  #pragma unroll
  for (int off = 32; off; off >>= 1){ ss += __shfl_down(ss, off); sd += __shfl_down(sd, off); }
  if (lane == 0){ als[n*H + wid] = ss; ald[n*H + wid] = sd; }
}

// ---------------- per-dst-node softmax + aggregate (wave-parallel) ----------------
template<int H, int C, bool CONCAT, bool DO_ELU>
__global__ __launch_bounds__(256)
void k_attn_agg(const unsigned short* __restrict__ hlin, int ldh,
                const float* __restrict__ als, const float* __restrict__ ald,
                const int* __restrict__ indptr, const int* __restrict__ csr_src,
                const float* __restrict__ bias,
                void* __restrict__ outv, int ldo, int col0){
  constexpr int TOT = H*C;
  constexpr int CHUNKS = TOT/4;
  constexpr int CPL = (CHUNKS + 63)/64;
  int n = blockIdx.x;
  int tid = threadIdx.x;
  int wv = tid >> 6, lane = tid & 63;
  int beg = indptr[n], end = indptr[n+1];

  __shared__ float s_m[H], s_dinv[H], s_ald[H];
  __shared__ float s_red[4][TOT];

  for (int h = wv; h < H; h += 4){
    float aldv = ald[n*H + h];
    float m = -1e30f, d = 0.f;
    for (int e = beg + lane; e < end; e += 64){
      int s = csr_src[e];
      float v = als[s*H + h] + aldv;
      v = v > 0.f ? v : 0.2f*v;
      if (v > m){ d *= __expf(m - v); m = v; }
      d += __expf(v - m);
    }
    #pragma unroll
    for (int off = 1; off < 64; off <<= 1){
      float mo = __shfl_xor(m, off);
      float dd = __shfl_xor(d, off);
      float mn = fmaxf(m, mo);
      d = d*__expf(m - mn) + dd*__expf(mo - mn);
      m = mn;
    }
    if (lane == 0){ s_m[h] = m; s_dinv[h] = 1.f/(d + 1e-16f); s_ald[h] = aldv; }
  }
  __syncthreads();

  int hof[CPL];
  #pragma unroll
  for (int p = 0; p < CPL; p++) hof[p] = ((lane + p*64)*4)/C;

  f32x4 acc[CPL];
  #pragma unroll
  for (int p = 0; p < CPL; p++) acc[p] = (f32x4){0.f,0.f,0.f,0.f};

  for (int e = beg + wv; e < end; e += 4){
    int s = csr_src[e];
    float al = 0.f;
    if (lane < H){
      float v = als[s*H + lane] + s_ald[lane];
      v = v > 0.f ? v : 0.2f*v;
      al = __expf(v - s_m[lane]) * s_dinv[lane];
    }
    float aph[CPL];
    #pragma unroll
    for (int p = 0; p < CPL; p++) aph[p] = __shfl(al, hof[p]);
    const bf16x4* hr = (const bf16x4*)(hlin + (size_t)s*ldh);
    #pragma unroll
    for (int p = 0; p < CPL; p++){
      int ch = lane + p*64;
      if (CHUNKS % 64 == 0 || ch < CHUNKS){
        bf16x4 hv = hr[ch];
        acc[p].x += bf2f((unsigned short)hv.x)*aph[p];
        acc[p].y += bf2f((unsigned short)hv.y)*aph[p];
        acc[p].z += bf2f((unsigned short)hv.z)*aph[p];
        acc[p].w += bf2f((unsigned short)hv.w)*aph[p];
      }
    }
  }

  #pragma unroll
  for (int p = 0; p < CPL; p++){
    int ch = lane + p*64;
    if (CHUNKS % 64 == 0 || ch < CHUNKS)
      *(f32x4*)&s_red[wv][ch*4] = acc[p];
  }
  __syncthreads();

  if (CONCAT){
    unsigned short* out = (unsigned short*)outv;
    constexpr int QS = (TOT + 255)/256;
    #pragma unroll
    for (int qq = 0; qq < QS; qq++){
      int idx = tid + qq*256;
      if (TOT % 256 == 0 || idx < TOT){
        float v = s_red[0][idx] + s_red[1][idx] + s_red[2][idx] + s_red[3][idx] + bias[idx];
        if (DO_ELU) v = elu_f(v);
        out[(size_t)n*ldo + col0 + idx] = f2bf(v);
      }
    }
  } else {
    float* out = (float*)outv;
    if (tid < C){
      float v = 0.f;
      #pragma unroll
      for (int h = 0; h < H; h++){
        int idx = h*C + tid;
        v += s_red[0][idx] + s_red[1][idx] + s_red[2][idx] + s_red[3][idx];
      }
      out[(size_t)n*ldo + tid] = v*(1.f/(float)H) + bias[tid];
    }
  }
}

// ---------------- launch ----------------
extern "C" void kernel_launch(void* const* d_in, const int* in_sizes, int n_in,
                              void* d_out, int out_size, void* d_ws, size_t ws_size,
                              hipStream_t stream){
  const float* x      = (const float*)d_in[0];
  const int*   ei     = (const int*)  d_in[1];
  const float* proj_W = (const float*)d_in[2];
  const float* proj_b = (const float*)d_in[3];
  const float* norm_w = (const float*)d_in[4];
  const float* norm_b = (const float*)d_in[5];
  const float* g1_W   = (const float*)d_in[6];
  const float* g1_as  = (const float*)d_in[7];
  const float* g1_ad  = (const float*)d_in[8];
  const float* g1_b   = (const float*)d_in[9];
  const float* g2_W   = (const float*)d_in[10];
  const float* g2_as  = (const float*)d_in[11];
  const float* g2_ad  = (const float*)d_in[12];
  const float* g2_b   = (const float*)d_in[13];
  const float* uni_W  = (const float*)d_in[14];
  const float* uni_b  = (const float*)d_in[15];
  const float* fnorm_w= (const float*)d_in[16];
  const float* fnorm_b= (const float*)d_in[17];
  const float* fg_W   = (const float*)d_in[18];
  const float* fg_as  = (const float*)d_in[19];
  const float* fg_ad  = (const float*)d_in[20];
  const float* fg_b   = (const float*)d_in[21];

  float* w = (float*)d_ws;
  float* h    = w; w += 7680000;
  float* h2   = w; w += 7680000;
  unsigned short* linbuf = (unsigned short*)w; w += 5120000;  // bf16 [10000,1024]/[10000,960]
  unsigned short* hnb  = (unsigned short*)w; w += 3840000;
  unsigned short* catb = (unsigned short*)w; w += 4800000;
  unsigned short* wb   = (unsigned short*)w; w += 3489792;
  float* als  = w; w += 80000;
  float* ald  = w; w += 80000;
  float* als2 = w; w += 80000;
  float* ald2 = w; w += 80000;
  int* iw = (int*)w;
  int* cnt     = iw; iw += 10016;
  int* indptr  = iw; iw += 10016;
  int* pos     = iw; iw += 10016;
  int* csr_src = iw; iw += 110016;

  unsigned short* wb_proj = wb;
  unsigned short* wb_l12  = wb_proj + 294912;   // 4 x [960][768]
  unsigned short* wb_uni  = wb_l12 + 2949120;
  unsigned short* wb_fg   = wb_uni + 2949120;

  // CSR
  hipMemsetAsync(cnt, 0, N_NODES*sizeof(int), stream);
  k_count<<<(E_TOT+255)/256, 256, 0, stream>>>(ei, cnt);
  k_scan<<<1, 1024, 0, stream>>>(cnt, indptr);
  k_copy_int<<<(N_NODES+255)/256, 256, 0, stream>>>(indptr, pos, N_NODES);
  k_fill<<<(E_TOT+255)/256, 256, 0, stream>>>(ei, pos, csr_src);

  // fp32 -> bf16 converts (vectorized)
  k_f2bf_arr4<<<(960000+255)/256, 256, 0, stream>>>((const float4*)x, (ushort4*)hnb, 960000);
  k_f2bf_arr4<<<(73728+255)/256,  256, 0, stream>>>((const float4*)proj_W, (ushort4*)wb_proj, 73728);
  k_pack_l1l2<<<(737280+255)/256, 256, 0, stream>>>(g1_W, g2_W, wb_l12);
  k_f2bf_arr4<<<(737280+255)/256, 256, 0, stream>>>((const float4*)uni_W, (ushort4*)wb_uni, 737280);
  k_f2bf_arr4<<<(196608+255)/256, 256, 0, stream>>>((const float4*)fg_W, (ushort4*)wb_fg, 196608);

  dim3 blk(256);
  const int GM = (N_NODES + 127) / 128;  // 79

  // h = elu(x @ proj_W.T + proj_b)
  k_gemm_mfma<1><<<dim3(6*GM), blk, 0, stream>>>(hnb, 384, wb_proj, h, 768, N_NODES, 768, 384, proj_b, nullptr, 0, 6);

  float* cur = h;
  float* oth = h2;
  for (int i = 0; i < 4; i++){
    k_layernorm_bf<<<N_NODES, 256, 0, stream>>>(cur, norm_w + i*768, norm_b + i*768, hnb);
    // combined [g1 | g2] GEMM: N = 960
    k_gemm_mfma<0><<<dim3(8*GM), blk, 0, stream>>>(hnb, 768, wb_l12 + (size_t)i*737280, linbuf, 960, N_NODES, 960, 768, nullptr, nullptr, 0, 8);
    k_attn_coef<4,192><<<N_NODES, 256, 0, stream>>>(linbuf, 960, g1_as + i*768, g1_ad + i*768, als, ald);
    k_attn_agg<4,192,true,true><<<N_NODES, 256, 0, stream>>>(linbuf, 960, als, ald, indptr, csr_src, g1_b + i*768, catb, 960, 0);
    k_attn_coef<2,96><<<N_NODES, 128, 0, stream>>>(linbuf + 768, 960, g2_as + i*192, g2_ad + i*192, als2, ald2);
    k_attn_agg<2,96,true,true><<<N_NODES, 256, 0, stream>>>(linbuf + 768, 960, als2, ald2, indptr, csr_src, g2_b + i*192, catb, 960, 768);
    k_gemm_mfma<2><<<dim3(6*GM), blk, 0, stream>>>(catb, 960, wb_uni + (size_t)i*737280, oth, 768, N_NODES, 768, 960, uni_b + i*768, cur, 768, 6);
    float* t = cur; cur = oth; oth = t;
  }

  k_layernorm_bf<<<N_NODES, 256, 0, stream>>>(cur, fnorm_w, fnorm_b, hnb);
  k_gemm_mfma<0><<<dim3(8*GM), blk, 0, stream>>>(hnb, 768, wb_fg, linbuf, 1024, N_NODES, 1024, 768, nullptr, nullptr, 0, 8);
  k_attn_coef<8,128><<<N_NODES, 512, 0, stream>>>(linbuf, 1024, fg_as, fg_ad, als, ald);
  k_attn_agg<8,128,false,false><<<N_NODES, 256, 0, stream>>>(linbuf, 1024, als, ald, indptr, csr_src, fg_b, d_out, 128, 0);
}